// Round 9
// baseline (1609.400 us; speedup 1.0000x reference)
//
#include <hip/hip_runtime.h>

typedef _Float16 f16;
typedef _Float16 f16x8 __attribute__((ext_vector_type(8)));
typedef _Float16 f16x4 __attribute__((ext_vector_type(4)));
typedef float f32x4 __attribute__((ext_vector_type(4)));

static constexpr int BB = 2, T = 1024, D = 1024, FFD = 4096, V = 32000, NL = 6;
static constexpr int M = BB * T;                       // 2048 rows
static constexpr int ROWS_PER_LAYER = 4*D + 2*FFD + D; // 13312 scale rows per layer
static constexpr size_t QL = 4ull*D*D + 2ull*FFD*D + (size_t)D*FFD; // 16.78M elems/layer
static constexpr int NT = 64, CT = T / NT;             // scan: 64 chunks x 16 steps
static constexpr int RKV = 3*D;                        // fused rkv row stride

// direct global->LDS, 16B per lane. lds base wave-uniform; HW writes lane i at
// lds + i*16 (m104).
__device__ __forceinline__ void gload16(const f16* g, f16* l) {
  __builtin_amdgcn_global_load_lds(
      (const __attribute__((address_space(1))) void*)g,
      (__attribute__((address_space(3))) void*)l, 16, 0, 0);
}
// counted vmcnt wait: allow the newest stage's N loads to remain in flight.
template<int N> __device__ __forceinline__ void vm_wait() {
  static_assert(N >= 2 && N <= 4, "unsupported vmcnt");
  if constexpr (N == 2) asm volatile("s_waitcnt vmcnt(2)" ::: "memory");
  else if constexpr (N == 3) asm volatile("s_waitcnt vmcnt(3)" ::: "memory");
  else                       asm volatile("s_waitcnt vmcnt(4)" ::: "memory");
}
// ring-phase boundary: all waves' reads of the oldest buffer are complete;
// sched_barrier pins the next stage AFTER the barrier.
__device__ __forceinline__ void ring_barrier() {
  __builtin_amdgcn_s_barrier();
  __builtin_amdgcn_sched_barrier(0);
}

// ---------------------------------------------------------------------------
// Single-pass per-row scale + ternary-quantize to f16 (row held in registers).
// qw layout per layer: [qr(D,D) qk qv qo | q1(FFD,D) q2 | qoc(D,FFD)]
// ---------------------------------------------------------------------------
__global__ __launch_bounds__(256) void quant_kernel(
    const float* __restrict__ Wr, const float* __restrict__ Wk,
    const float* __restrict__ Wv, const float* __restrict__ Wo,
    const float* __restrict__ W1, const float* __restrict__ W2,
    const float* __restrict__ Woc, f16* __restrict__ qw, float* __restrict__ scales)
{
  const int r = blockIdx.x, l = blockIdx.y;
  const float* base; int len; size_t dst;
  if (r < 4*D) {
    const int m = r >> 10, row = r & (D-1);
    const float* Wm = (m==0) ? Wr : (m==1) ? Wk : (m==2) ? Wv : Wo;
    base = Wm + (size_t)l*D*D + (size_t)row*D; len = D;
    dst = (size_t)l*QL + (size_t)m*D*D + (size_t)row*D;
  } else if (r < 4*D + 2*FFD) {
    int row = r - 4*D;
    const int m = row >= FFD; if (m) row -= FFD;
    const float* Wm = m ? W2 : W1;
    base = Wm + (size_t)l*FFD*D + (size_t)row*D; len = D;
    dst = (size_t)l*QL + 4ull*D*D + (size_t)m*FFD*D + (size_t)row*D;
  } else {
    const int row = r - (4*D + 2*FFD);
    base = Woc + (size_t)l*D*FFD + (size_t)row*FFD; len = FFD;
    dst = (size_t)l*QL + 4ull*D*D + 2ull*FFD*D + (size_t)row*FFD;
  }
  const int nv = len >> 10;
  float4 rv[4];
  float sum = 0.f;
  #pragma unroll 4
  for (int i = 0; i < 4; ++i) {
    if (i < nv) {
      rv[i] = reinterpret_cast<const float4*>(base)[threadIdx.x + i*256];
      sum += fabsf(rv[i].x) + fabsf(rv[i].y) + fabsf(rv[i].z) + fabsf(rv[i].w);
    }
  }
  #pragma unroll
  for (int off = 32; off > 0; off >>= 1) sum += __shfl_down(sum, off);
  __shared__ float red[4]; __shared__ float sbc;
  if ((threadIdx.x & 63) == 0) red[threadIdx.x >> 6] = sum;
  __syncthreads();
  if (threadIdx.x == 0) {
    const float s = fmaxf((red[0]+red[1]+red[2]+red[3]) / (float)len, 1e-5f);
    sbc = s;
    scales[(size_t)l*ROWS_PER_LAYER + r] = s;
  }
  __syncthreads();
  const float hs = 0.5f * sbc;
  #pragma unroll 4
  for (int i = 0; i < 4; ++i) {
    if (i < nv) {
      const float4 v = rv[i];
      f16x4 q;
      q[0] = v.x > hs ? (f16)1.f : (v.x < -hs ? (f16)-1.f : (f16)0.f);
      q[1] = v.y > hs ? (f16)1.f : (v.y < -hs ? (f16)-1.f : (f16)0.f);
      q[2] = v.z > hs ? (f16)1.f : (v.z < -hs ? (f16)-1.f : (f16)0.f);
      q[3] = v.w > hs ? (f16)1.f : (v.w < -hs ? (f16)-1.f : (f16)0.f);
      reinterpret_cast<f16x4*>(qw + dst)[threadIdx.x + i*256] = q;
    }
  }
}

// f32 -> f16 bulk convert (for embed / head B operand)
__global__ __launch_bounds__(256) void cvt16_kernel(
    const float* __restrict__ x, f16* __restrict__ o, int n4)
{
  const int stride = gridDim.x * 256;
  for (int i = blockIdx.x*256 + threadIdx.x; i < n4; i += stride) {
    const float4 v = reinterpret_cast<const float4*>(x)[i];
    f16x4 q; q[0]=(f16)v.x; q[1]=(f16)v.y; q[2]=(f16)v.z; q[3]=(f16)v.w;
    reinterpret_cast<f16x4*>(o)[i] = q;
  }
}

// ---------------------------------------------------------------------------
// h = rmsnorm(embed[idx], ln_in_w), f32 out. One block (256 thr) per row.
// ---------------------------------------------------------------------------
__global__ __launch_bounds__(256) void embed_rms_kernel(
    const int* __restrict__ idx, const float* __restrict__ embed,
    const float* __restrict__ g, float* __restrict__ h)
{
  const int row = blockIdx.x;
  const int tok = idx[row];
  const float4 xv = reinterpret_cast<const float4*>(embed + (size_t)tok*D)[threadIdx.x];
  float ss = xv.x*xv.x + xv.y*xv.y + xv.z*xv.z + xv.w*xv.w;
  #pragma unroll
  for (int off = 32; off > 0; off >>= 1) ss += __shfl_down(ss, off);
  __shared__ float red[4];
  if ((threadIdx.x & 63) == 0) red[threadIdx.x >> 6] = ss;
  __syncthreads();
  const float mean = (red[0]+red[1]+red[2]+red[3]) * (1.f/(float)D);
  const float rn = rsqrtf(mean + 1e-6f);
  const float4 gv = reinterpret_cast<const float4*>(g)[threadIdx.x];
  float4 ov;
  ov.x = xv.x*rn*gv.x; ov.y = xv.y*rn*gv.y; ov.z = xv.z*rn*gv.z; ov.w = xv.w*rn*gv.w;
  reinterpret_cast<float4*>(h + (size_t)row*D)[threadIdx.x] = ov;
}

// ---------------------------------------------------------------------------
// xn = (f16) rmsnorm(x, g). One block (256 thr) per row of 1024.
// ---------------------------------------------------------------------------
__global__ __launch_bounds__(256) void rms_f16_kernel(
    const float* __restrict__ x, const float* __restrict__ g, f16* __restrict__ o)
{
  const int row = blockIdx.x;
  const float4 xv = reinterpret_cast<const float4*>(x + (size_t)row*D)[threadIdx.x];
  float ss = xv.x*xv.x + xv.y*xv.y + xv.z*xv.z + xv.w*xv.w;
  #pragma unroll
  for (int off = 32; off > 0; off >>= 1) ss += __shfl_down(ss, off);
  __shared__ float red[4];
  if ((threadIdx.x & 63) == 0) red[threadIdx.x >> 6] = ss;
  __syncthreads();
  const float mean = (red[0]+red[1]+red[2]+red[3]) * (1.f/(float)D);
  const float rn = rsqrtf(mean + 1e-6f);
  const float4 gv = reinterpret_cast<const float4*>(g)[threadIdx.x];
  f16x4 ov;
  ov[0] = (f16)(xv.x*rn*gv.x); ov[1] = (f16)(xv.y*rn*gv.y);
  ov[2] = (f16)(xv.z*rn*gv.z); ov[3] = (f16)(xv.w*rn*gv.w);
  reinterpret_cast<f16x4*>(o + (size_t)row*D)[threadIdx.x] = ov;
}

// ---------------------------------------------------------------------------
// Fused: h += p0 + p1; xn = (f16) rmsnorm(h, g).
// ---------------------------------------------------------------------------
__global__ __launch_bounds__(256) void rms_radd_kernel(
    float* __restrict__ h, const float* __restrict__ p0,
    const float* __restrict__ p1, const float* __restrict__ g,
    f16* __restrict__ o)
{
  const int row = blockIdx.x;
  const size_t off = (size_t)row*D/4 + threadIdx.x;
  float4 hv = reinterpret_cast<const float4*>(h)[off];
  const float4 a = reinterpret_cast<const float4*>(p0)[off];
  const float4 b = reinterpret_cast<const float4*>(p1)[off];
  hv.x += a.x + b.x; hv.y += a.y + b.y; hv.z += a.z + b.z; hv.w += a.w + b.w;
  reinterpret_cast<float4*>(h)[off] = hv;
  float ss = hv.x*hv.x + hv.y*hv.y + hv.z*hv.z + hv.w*hv.w;
  #pragma unroll
  for (int o2 = 32; o2 > 0; o2 >>= 1) ss += __shfl_down(ss, o2);
  __shared__ float red[4];
  if ((threadIdx.x & 63) == 0) red[threadIdx.x >> 6] = ss;
  __syncthreads();
  const float mean = (red[0]+red[1]+red[2]+red[3]) * (1.f/(float)D);
  const float rn = rsqrtf(mean + 1e-6f);
  const float4 gv = reinterpret_cast<const float4*>(g)[threadIdx.x];
  f16x4 ov;
  ov[0] = (f16)(hv.x*rn*gv.x); ov[1] = (f16)(hv.y*rn*gv.y);
  ov[2] = (f16)(hv.z*rn*gv.z); ov[3] = (f16)(hv.w*rn*gv.w);
  reinterpret_cast<f16x4*>(o + (size_t)row*D)[threadIdx.x] = ov;
}

// ---------------------------------------------------------------------------
// Time-mix recurrence: chunked prefix sum over T.
// ---------------------------------------------------------------------------
__global__ __launch_bounds__(256) void scan1_kernel(
    const float* __restrict__ k, const float* __restrict__ v, int ld,
    const float* __restrict__ decay, float* __restrict__ part)
{
  const int d = blockIdx.x*256 + threadIdx.x;
  const int c = blockIdx.y, b = blockIdx.z;
  const float dec = 1.f / (1.f + expf(-decay[d]));
  const float ldc = logf(fmaxf(dec, 1e-7f));
  float sum = 0.f;
  const int row0 = b*T + c*CT;
  #pragma unroll 4
  for (int t = 0; t < CT; ++t) {
    const size_t i = (size_t)(row0 + t)*ld + d;
    const float scale = expf((float)(c*CT + t) * ldc);
    sum += (k[i] * v[i]) / fmaxf(scale, 1e-10f);
  }
  part[((size_t)b*NT + c)*D + d] = sum;
}

__global__ __launch_bounds__(256) void scan23_kernel(
    const float* __restrict__ r, const float* __restrict__ k,
    const float* __restrict__ v, int ld, const float* __restrict__ decay,
    const float* __restrict__ part, float* __restrict__ rs)
{
  const int d = blockIdx.x*256 + threadIdx.x;
  const int c = blockIdx.y, b = blockIdx.z;
  const float dec = 1.f / (1.f + expf(-decay[d]));
  const float ldc = logf(fmaxf(dec, 1e-7f));
  float cum = 0.f;
  for (int j = 0; j < c; ++j) cum += part[((size_t)b*NT + j)*D + d];
  const int row0 = b*T + c*CT;
  #pragma unroll 4
  for (int t = 0; t < CT; ++t) {
    const size_t i = (size_t)(row0 + t)*ld + d;
    const float scale = expf((float)(c*CT + t) * ldc);
    cum += (k[i] * v[i]) / fmaxf(scale, 1e-10f);
    rs[(size_t)(row0 + t)*D + d] = r[i] * (cum * scale);
  }
}

// fallback-path kernels -------------------------------------------------------
__global__ __launch_bounds__(256) void scan2_kernel(float* __restrict__ part)
{
  const int d = blockIdx.x*256 + threadIdx.x;
  const int b = blockIdx.y;
  float run = 0.f;
  #pragma unroll 8
  for (int c = 0; c < NT; ++c) {
    const size_t i = ((size_t)b*NT + c)*D + d;
    const float t = part[i];
    part[i] = run;
    run += t;
  }
}

__global__ __launch_bounds__(256) void scan3_kernel(
    const float* __restrict__ r, const float* __restrict__ k,
    const float* __restrict__ v, int ld, const float* __restrict__ decay,
    const float* __restrict__ part, float* __restrict__ rs)
{
  const int d = blockIdx.x*256 + threadIdx.x;
  const int c = blockIdx.y, b = blockIdx.z;
  const float dec = 1.f / (1.f + expf(-decay[d]));
  const float ldc = logf(fmaxf(dec, 1e-7f));
  float cum = part[((size_t)b*NT + c)*D + d];
  const int row0 = b*T + c*CT;
  #pragma unroll 4
  for (int t = 0; t < CT; ++t) {
    const size_t i = (size_t)(row0 + t)*ld + d;
    const float scale = expf((float)(c*CT + t) * ldc);
    cum += (k[i] * v[i]) / fmaxf(scale, 1e-10f);
    rs[(size_t)(row0 + t)*D + d] = r[i] * (cum * scale);
  }
}

__global__ __launch_bounds__(256) void silumul_kernel(
    const f16* __restrict__ a, const f16* __restrict__ b, f16* __restrict__ o, int n4)
{
  const int i = blockIdx.x*256 + threadIdx.x;
  if (i >= n4) return;
  const f16x4 av = reinterpret_cast<const f16x4*>(a)[i];
  const f16x4 bv = reinterpret_cast<const f16x4*>(b)[i];
  f16x4 ov;
  #pragma unroll
  for (int j = 0; j < 4; ++j) {
    const float x = (float)av[j];
    ov[j] = (f16)((x / (1.f + expf(-x))) * (float)bv[j]);
  }
  reinterpret_cast<f16x4*>(o)[i] = ov;
}

// ---------------------------------------------------------------------------
// XCD-chunked bijective block swizzle (m204).
// ---------------------------------------------------------------------------
__device__ __forceinline__ int xcd_swizzle(int fid, int nwg) {
  const int q = nwg >> 3, r = nwg & 7, x = fid & 7, o = fid >> 3;
  return (x < r ? x*(q+1) : r*(q+1) + (x-r)*q) + o;
}

// ---------------------------------------------------------------------------
// RING GEMM (3-buffer, depth-2 prefetch, counted vmcnt, ONE barrier/K-step):
// out[M,N] = epi(scl[n] * A[M,K] @ Bq[N,K]^T). BK=32, linear LDS, BN=128,
// NW=8 waves (WN=2 x WM=4). BM in {128, 256}. EPI: 0 none, 2 +resid,
// 3 sigmoid iff col<D. SPLITK: gridDim.z pieces write outp + z*M*N.
// Tile geometry chosen for L2-BW-bound regime (round-8 analysis): intensity
// = MFMA-cy per staged byte scales with BM*BN/(BM+BN).
// ---------------------------------------------------------------------------
template<int BM, int EPI, bool OUTF16, bool SCALE, bool SPLITK = false>
__global__ __launch_bounds__(512) void gemm_q_kernel(
    const f16* __restrict__ A, const f16* __restrict__ Bq,
    const float* __restrict__ scl, const float* __restrict__ resid,
    void* __restrict__ outp, int N, int K)
{
  constexpr int NW = 8, WN = 2;
  constexpr int WM = NW / WN;            // 4
  constexpr int MF = BM / (WM*16);       // 2 (BM=128) or 4 (BM=256)
  constexpr int ACALLS = BM / (16*NW);   // 1 or 2
  constexpr int BCALLS = 1;
  constexpr int VCNT = ACALLS + BCALLS;  // 2 or 3
  __shared__ f16 As[3][BM*32];
  __shared__ f16 Bs[3][128*32];

  const int tid = threadIdx.x;
  const int wave = tid >> 6, lane = tid & 63;
  const int gx = gridDim.x, nwg = gx * gridDim.y;
  const int wg = xcd_swizzle(blockIdx.x + blockIdx.y*gx, nwg);
  const int m0 = (wg % gx) * BM, n0 = (wg / gx) * 128;
  const int lr = lane & 15, kg = lane >> 4;
  const int wm0 = (wave / WN) * (MF*16), wn0 = (wave % WN) * 64;
  const int grow = lane >> 2;
  const int gcol = (lane & 3) * 8;
  const f16* Ab = A  + (size_t)(m0 + grow)*K + gcol;
  const f16* Bb = Bq + (size_t)(n0 + grow)*K + gcol;

  int kbeg = 0, kend = K;
  size_t obase = 0;
  if (SPLITK) {
    const int kc = K / gridDim.z;
    kbeg = blockIdx.z * kc; kend = kbeg + kc;
    obase = (size_t)blockIdx.z * M * (size_t)N;
  }
  const int NKT = (kend - kbeg) / 32;

  auto stage = [&](int buf, int k0) {
    #pragma unroll
    for (int c = 0; c < ACALLS; ++c) {
      const int rb = (c*NW + wave) * 16;
      gload16(Ab + (size_t)rb*K + k0, &As[buf][rb*32]);
    }
    gload16(Bb + (size_t)(wave*16)*K + k0, &Bs[buf][(wave*16)*32]);
  };

  f32x4 acc[MF][4] = {};
  stage(0, kbeg);
  stage(1, kbeg + 32);

  int cur = 0;
  for (int t = 0; t < NKT; ++t) {
    vm_wait<VCNT>();
    ring_barrier();
    if (t + 2 < NKT) {
      int nb = cur + 2; if (nb >= 3) nb -= 3;
      stage(nb, kbeg + (t + 2) * 32);
    }
    f16x8 af[MF], bf[4];
    #pragma unroll
    for (int i = 0; i < MF; ++i)
      af[i] = *reinterpret_cast<const f16x8*>(&As[cur][(wm0 + i*16 + lr)*32 + kg*8]);
    #pragma unroll
    for (int j = 0; j < 4; ++j)
      bf[j] = *reinterpret_cast<const f16x8*>(&Bs[cur][(wn0 + j*16 + lr)*32 + kg*8]);
    #pragma unroll
    for (int i = 0; i < MF; ++i)
      #pragma unroll
      for (int j = 0; j < 4; ++j)
        acc[i][j] = __builtin_amdgcn_mfma_f32_16x16x32_f16(af[i], bf[j], acc[i][j], 0, 0, 0);
    ++cur; if (cur == 3) cur = 0;
  }

  // C/D frag layout: col=lane&15, row=(lane>>4)*4+e
  #pragma unroll
  for (int j = 0; j < 4; ++j) {
    const int col = n0 + wn0 + j*16 + lr;
    const float sv = SCALE ? scl[col] : 1.f;
    #pragma unroll
    for (int i = 0; i < MF; ++i) {
      #pragma unroll
      for (int e = 0; e < 4; ++e) {
        const int row = m0 + wm0 + i*16 + kg*4 + e;
        float y = acc[i][j][e] * sv;
        if (EPI == 3 && col < D) y = 1.f / (1.f + expf(-y));
        if (EPI == 2) y += resid[(size_t)row*N + col];
        if (OUTF16) reinterpret_cast<f16*>(outp)[(size_t)row*N + col] = (f16)y;
        else        reinterpret_cast<float*>(outp)[obase + (size_t)row*N + col] = y;
      }
    }
  }
}

// ---------------------------------------------------------------------------
// RING HEAD GEMM: 256x256 tile, 8 waves (2M x 4N), 3-buffer ring.
// 96KB LDS, acc 128 VGPR -> 1 block/CU; intensity 1.5x the 128x256 shape.
// ---------------------------------------------------------------------------
__global__ __launch_bounds__(512) void gemm_head_kernel(
    const f16* __restrict__ A, const f16* __restrict__ Bq,
    float* __restrict__ out, int N, int K)
{
  __shared__ f16 As[3][256*32];
  __shared__ f16 Bs[3][256*32];
  const int tid = threadIdx.x;
  const int wave = tid >> 6, lane = tid & 63;
  const int gx = gridDim.x, nwg = gx * gridDim.y;
  const int wg = xcd_swizzle(blockIdx.x + blockIdx.y*gx, nwg);
  const int m0 = (wg % gx) * 256, n0 = (wg / gx) * 256;
  const int lr = lane & 15, kg = lane >> 4;
  const int wm0 = (wave >> 2) * 128, wn0 = (wave & 3) * 64;
  const int grow = lane >> 2, gcol = (lane & 3) * 8;
  const f16* Ab = A  + (size_t)(m0 + grow)*K + gcol;
  const f16* Bb = Bq + (size_t)(n0 + grow)*K + gcol;

  auto stage = [&](int buf, int k0) {
    #pragma unroll
    for (int c = 0; c < 2; ++c) {
      const int rb = (c*8 + wave) * 16;
      gload16(Ab + (size_t)rb*K + k0, &As[buf][rb*32]);
      gload16(Bb + (size_t)rb*K + k0, &Bs[buf][rb*32]);
    }
  };

  f32x4 acc[8][4] = {};
  stage(0, 0);
  stage(1, 32);

  const int NKT = K / 32;
  int cur = 0;
  for (int t = 0; t < NKT; ++t) {
    vm_wait<4>();
    ring_barrier();
    if (t + 2 < NKT) {
      int nb = cur + 2; if (nb >= 3) nb -= 3;
      stage(nb, (t + 2) * 32);
    }
    f16x8 af[8], bf[4];
    #pragma unroll
    for (int i = 0; i < 8; ++i)
      af[i] = *reinterpret_cast<const f16x8*>(&As[cur][(wm0 + i*16 + lr)*32 + kg*8]);
    #pragma unroll
    for (int j = 0; j < 4; ++j)
      bf[j] = *reinterpret_cast<const f16x8*>(&Bs[cur][(wn0 + j*16 + lr)*32 + kg*8]);
    #pragma unroll
    for (int i = 0; i < 8; ++i)
      #pragma unroll
      for (int j = 0; j < 4; ++j)
        acc[i][j] = __builtin_amdgcn_mfma_f32_16x16x32_f16(af[i], bf[j], acc[i][j], 0, 0, 0);
    ++cur; if (cur == 3) cur = 0;
  }
  #pragma unroll
  for (int j = 0; j < 4; ++j) {
    const int col = n0 + wn0 + j*16 + lr;
    #pragma unroll
    for (int i = 0; i < 8; ++i) {
      #pragma unroll
      for (int e = 0; e < 4; ++e) {
        const int row = m0 + wm0 + i*16 + kg*4 + e;
        out[(size_t)row*N + col] = acc[i][j][e];
      }
    }
  }
}

// ---------------------------------------------------------------------------
// RING FUSED FFN GEMM: g = (f16)( silu(s1[n]*A@B1^T) * (s2[n]*A@B2^T) ).
// 256x128 tile, 8 waves (4M x 2N, per-wave 64x64 per accumulator), ring-3.
// ---------------------------------------------------------------------------
__global__ __launch_bounds__(512) void gemm_ffn_kernel(
    const f16* __restrict__ A, const f16* __restrict__ B1, const f16* __restrict__ B2,
    const float* __restrict__ s1, const float* __restrict__ s2,
    f16* __restrict__ outg, int N, int K)
{
  __shared__ f16 As [3][256*32];
  __shared__ f16 B1s[3][128*32];
  __shared__ f16 B2s[3][128*32];
  const int tid = threadIdx.x;
  const int wave = tid >> 6, lane = tid & 63;
  const int gx = gridDim.x, nwg = gx * gridDim.y;
  const int wg = xcd_swizzle(blockIdx.x + blockIdx.y*gx, nwg);
  const int m0 = (wg % gx) * 256, n0 = (wg / gx) * 128;
  const int lr = lane & 15, kg = lane >> 4;
  const int wm0 = (wave >> 1) * 64, wn0 = (wave & 1) * 64;
  const int grow = lane >> 2, gcol = (lane & 3) * 8;
  const f16* Ab  = A  + (size_t)(m0 + grow)*K + gcol;
  const f16* B1b = B1 + (size_t)(n0 + grow)*K + gcol;
  const f16* B2b = B2 + (size_t)(n0 + grow)*K + gcol;

  auto stage = [&](int buf, int k0) {
    #pragma unroll
    for (int c = 0; c < 2; ++c) {
      const int rb = (c*8 + wave) * 16;
      gload16(Ab + (size_t)rb*K + k0, &As[buf][rb*32]);
    }
    const int rb = wave * 16;
    gload16(B1b + (size_t)rb*K + k0, &B1s[buf][rb*32]);
    gload16(B2b + (size_t)rb*K + k0, &B2s[buf][rb*32]);
  };

  f32x4 aca[4][4] = {};
  f32x4 acb[4][4] = {};
  stage(0, 0);
  stage(1, 32);

  const int NKT = K / 32;
  int cur = 0;
  for (int t = 0; t < NKT; ++t) {
    vm_wait<4>();
    ring_barrier();
    if (t + 2 < NKT) {
      int nb = cur + 2; if (nb >= 3) nb -= 3;
      stage(nb, (t + 2) * 32);
    }
    f16x8 af[4], b1f[4], b2f[4];
    #pragma unroll
    for (int i = 0; i < 4; ++i)
      af[i] = *reinterpret_cast<const f16x8*>(&As[cur][(wm0 + i*16 + lr)*32 + kg*8]);
    #pragma unroll
    for (int j = 0; j < 4; ++j) {
      b1f[j] = *reinterpret_cast<const f16x8*>(&B1s[cur][(wn0 + j*16 + lr)*32 + kg*8]);
      b2f[j] = *reinterpret_cast<const f16x8*>(&B2s[cur][(wn0 + j*16 + lr)*32 + kg*8]);
    }
    #pragma unroll
    for (int i = 0; i < 4; ++i)
      #pragma unroll
      for (int j = 0; j < 4; ++j) {
        aca[i][j] = __builtin_amdgcn_mfma_f32_16x16x32_f16(af[i], b1f[j], aca[i][j], 0, 0, 0);
        acb[i][j] = __builtin_amdgcn_mfma_f32_16x16x32_f16(af[i], b2f[j], acb[i][j], 0, 0, 0);
      }
    ++cur; if (cur == 3) cur = 0;
  }
  #pragma unroll
  for (int j = 0; j < 4; ++j) {
    const int col = n0 + wn0 + j*16 + lr;
    const float sa = s1[col], sb = s2[col];
    #pragma unroll
    for (int i = 0; i < 4; ++i) {
      #pragma unroll
      for (int e = 0; e < 4; ++e) {
        const int row = m0 + wm0 + i*16 + kg*4 + e;
        const float a = aca[i][j][e] * sa;
        const float b = acb[i][j][e] * sb;
        outg[(size_t)row*N + col] = (f16)((a / (1.f + expf(-a))) * b);
      }
    }
  }
}

// ---------------------------------------------------------------------------
// FALLBACK GEMM: inline quantize from f32 weights (used if ws too small).
// ---------------------------------------------------------------------------
__global__ __launch_bounds__(64) void scales_kernel(
    const float* __restrict__ Wr, const float* __restrict__ Wk,
    const float* __restrict__ Wv, const float* __restrict__ Wo,
    const float* __restrict__ W1, const float* __restrict__ W2,
    const float* __restrict__ Woc, float* __restrict__ s)
{
  const int r = blockIdx.x, l = blockIdx.y;
  const float* base; int len;
  if (r < 4*D) {
    const int m = r >> 10, row = r & (D-1);
    const float* Wm = (m==0) ? Wr : (m==1) ? Wk : (m==2) ? Wv : Wo;
    base = Wm + (size_t)l*D*D + (size_t)row*D; len = D;
  } else if (r < 4*D + 2*FFD) {
    int row = r - 4*D;
    const float* Wm = (row < FFD) ? W1 : W2;
    if (row >= FFD) row -= FFD;
    base = Wm + (size_t)l*FFD*D + (size_t)row*D; len = D;
  } else {
    const int row = r - (4*D + 2*FFD);
    base = Woc + (size_t)l*D*FFD + (size_t)row*FFD; len = FFD;
  }
  float sum = 0.f;
  for (int i = threadIdx.x; i < len; i += 64) sum += fabsf(base[i]);
  #pragma unroll
  for (int off = 32; off > 0; off >>= 1) sum += __shfl_down(sum, off);
  if (threadIdx.x == 0)
    s[(size_t)l*ROWS_PER_LAYER + r] = fmaxf(sum / (float)len, 1e-5f);
}

template<int BM, int EPI, bool QUANT, bool OUTF16>
__global__ __launch_bounds__(256) void gemm_bt_kernel(
    const f16* __restrict__ A, const float* __restrict__ Bw,
    const float* __restrict__ scl, const float* __restrict__ resid,
    void* __restrict__ outp, int N, int K)
{
  constexpr int BN = 128, LDT = 40;
  constexpr int MF = (BM == 128) ? 4 : 2;
  __shared__ f16 As[BM*LDT];
  __shared__ f16 Bs[BN*LDT];
  const int tid = threadIdx.x;
  const int m0 = blockIdx.y * BM, n0 = blockIdx.x * BN;
  const int wave = tid >> 6, lane = tid & 63;
  const int lr = lane & 15, kg = lane >> 4;
  const int wm0 = (wave >> 1) * (MF*16), wn0 = (wave & 1) * 64;
  f32x4 acc[MF][4] = {};
  for (int k0 = 0; k0 < K; k0 += 32) {
    #pragma unroll
    for (int c = 0; c < (BM*4)/256; ++c) {
      const int chunk = tid + c*256;
      const int row = chunk >> 2, c8 = (chunk & 3) << 3;
      *reinterpret_cast<f16x8*>(&As[row*LDT + c8]) =
        *reinterpret_cast<const f16x8*>(A + (size_t)(m0+row)*K + k0 + c8);
    }
    #pragma unroll
    for (int c = 0; c < 2; ++c) {
      const int chunk = tid + c*256;
      const int row = chunk >> 2, c8 = (chunk & 3) << 3;
      const float* bp = Bw + (size_t)(n0+row)*K + k0 + c8;
      const float4 f0 = *reinterpret_cast<const float4*>(bp);
      const float4 f1 = *reinterpret_cast<const float4*>(bp + 4);
      const float wv[8] = {f0.x,f0.y,f0.z,f0.w,f1.x,f1.y,f1.z,f1.w};
      f16x8 qv;
      if (QUANT) {
        const float hs = 0.5f * scl[n0+row];
        #pragma unroll
        for (int j = 0; j < 8; ++j)
          qv[j] = wv[j] > hs ? (f16)1.f : (wv[j] < -hs ? (f16)(-1.f) : (f16)0.f);
      } else {
        #pragma unroll
        for (int j = 0; j < 8; ++j) qv[j] = (f16)wv[j];
      }
      *reinterpret_cast<f16x8*>(&Bs[row*LDT + c8]) = qv;
    }
    __syncthreads();
    f16x8 af[MF], bf[4];
    #pragma unroll
    for (int i = 0; i < MF; ++i)
      af[i] = *reinterpret_cast<const f16x8*>(&As[(wm0 + i*16 + lr)*LDT + kg*8]);
    #pragma unroll
    for (int j = 0; j < 4; ++j)
      bf[j] = *reinterpret_cast<const f16x8*>(&Bs[(wn0 + j*16 + lr)*LDT + kg*8]);
    #pragma unroll
    for (int i = 0; i < MF; ++i)
      #pragma unroll
      for (int j = 0; j < 4; ++j)
        acc[i][j] = __builtin_amdgcn_mfma_f32_16x16x32_f16(af[i], bf[j], acc[i][j], 0, 0, 0);
    __syncthreads();
  }
  #pragma unroll
  for (int j = 0; j < 4; ++j) {
    const int col = n0 + wn0 + j*16 + lr;
    const float sv = QUANT ? scl[col] : 1.f;
    #pragma unroll
    for (int i = 0; i < MF; ++i) {
      #pragma unroll
      for (int e = 0; e < 4; ++e) {
        const int row = m0 + wm0 + i*16 + kg*4 + e;
        float y = acc[i][j][e] * sv;
        if (EPI == 1) y = 1.f / (1.f + expf(-y));
        if (EPI == 2) y += resid[(size_t)row*N + col];
        if (OUTF16) reinterpret_cast<f16*>(outp)[(size_t)row*N + col] = (f16)y;
        else        reinterpret_cast<float*>(outp)[(size_t)row*N + col] = y;
      }
    }
  }
}

// ---------------------------------------------------------------------------
extern "C" void kernel_launch(void* const* d_in, const int* in_sizes, int n_in,
                              void* d_out, int out_size, void* d_ws, size_t ws_size,
                              hipStream_t stream)
{
  (void)in_sizes; (void)n_in; (void)out_size;
  const int*   idx      = (const int*)  d_in[0];
  const float* embed    = (const float*)d_in[1];
  const float* ln_in_w  = (const float*)d_in[2];
  const float* ln1_w    = (const float*)d_in[3];
  const float* Wr       = (const float*)d_in[4];
  const float* Wk       = (const float*)d_in[5];
  const float* Wv       = (const float*)d_in[6];
  const float* Wo_t     = (const float*)d_in[7];
  const float* decay    = (const float*)d_in[8];
  const float* lnx_w    = (const float*)d_in[9];
  const float* ln2_w    = (const float*)d_in[10];
  const float* W1       = (const float*)d_in[11];
  const float* W2       = (const float*)d_in[12];
  const float* Wo_c     = (const float*)d_in[13];
  const float* ln_out_w = (const float*)d_in[14];
  float* out = (float*)d_out;

  char* p = (char*)d_ws;
  auto alloc = [&](size_t bytes) { void* q = (void*)p; p += (bytes + 255) & ~(size_t)255; return q; };
  float* h      = (float*)alloc((size_t)M*D*sizeof(float));
  f16*   xn     = (f16*)  alloc((size_t)M*D*sizeof(f16));
  float* rkv    = (float*)alloc((size_t)M*RKV*sizeof(float));   // r|k|v; reused as split-K partials
  float* rsb    = (float*)alloc((size_t)M*D*sizeof(float));
  f16*   abf    = (f16*)  alloc((size_t)M*FFD*sizeof(f16));
  f16*   bbf    = (f16*)  alloc((size_t)M*FFD*sizeof(f16));     // fallback only
  float* scales = (float*)alloc((size_t)NL*ROWS_PER_LAYER*sizeof(float));
  float* part   = (float*)alloc((size_t)BB*NT*D*sizeof(float));
  const size_t base_need = (size_t)(p - (char*)d_ws);
  const size_t fast_need = base_need + (NL*QL*sizeof(f16) + 256) + ((size_t)V*D*sizeof(f16) + 256);

  embed_rms_kernel<<<M, 256, 0, stream>>>(idx, embed, ln_in_w, h);

  const dim3 gS(D/256, NT, BB);   // scan1/scan23: 512 blocks
  const dim3 gS2(D/256, BB);      // scan2 (fallback): 8 blocks

  if (ws_size >= fast_need) {
    // ================= FAST PATH: pre-quantized f16 weights =================
    f16* qw      = (f16*)alloc(NL*QL*sizeof(f16));
    f16* embed16 = (f16*)alloc((size_t)V*D*sizeof(f16));
    quant_kernel<<<dim3(ROWS_PER_LAYER, NL), 256, 0, stream>>>(Wr, Wk, Wv, Wo_t, W1, W2, Wo_c, qw, scales);
    cvt16_kernel<<<2048, 256, 0, stream>>>(embed, embed16, V*D/4);

    const dim3 gRKV(M/256, RKV/128);     // 8 x 24 = 192 blocks
    const dim3 gO(M/128, D/128, 2);      // 16 x 8 x 2 = 256 blocks (split-K)
    const dim3 gFFN(M/256, FFD/128);     // 8 x 32 = 256 blocks
    const dim3 gOC(M/128, D/128, 2);     // 256 blocks (split-K)
    const dim3 gHEAD(M/256, V/256);      // 8 x 125 = 1000 blocks

    float* pk0 = rkv;                    // split-K partials (rkv dead by then)
    float* pk1 = rkv + (size_t)M*D;

    rms_f16_kernel<<<M, 256, 0, stream>>>(h, ln1_w, xn);   // first layer's ln1
    for (int l = 0; l < NL; ++l) {
      const float* sl = scales + (size_t)l*ROWS_PER_LAYER;
      const f16* qb = qw + (size_t)l*QL;
      const f16 *qrkv = qb, *qo = qb + 3ull*D*D;
      const f16 *q1 = qb + 4ull*D*D, *q2 = qb + 4ull*D*D + (size_t)FFD*D;
      const f16 *qoc = qb + 4ull*D*D + 2ull*(size_t)FFD*D;
      const float* dcy = decay + (size_t)l*D;
      // ---- time mix ----
      gemm_q_kernel<256,3,false,true><<<gRKV, 512, 0, stream>>>(xn, qrkv, sl, nullptr, rkv, RKV, D);
      scan1_kernel<<<gS, 256, 0, stream>>>(rkv + D, rkv + 2*D, RKV, dcy, part);
      scan23_kernel<<<gS, 256, 0, stream>>>(rkv, rkv + D, rkv + 2*D, RKV, dcy, part, rsb);
      rms_f16_kernel<<<M, 256, 0, stream>>>(rsb, lnx_w + (size_t)l*D, xn);
      // o: split-K x2 into partials (rkv dead after scan23), resid fused below
      gemm_q_kernel<128,0,false,true,true><<<gO, 512, 0, stream>>>(xn, qo, sl + 3*D, nullptr, pk0, D, D);
      rms_radd_kernel<<<M, 256, 0, stream>>>(h, pk0, pk1, ln2_w + (size_t)l*D, xn);
      // ---- channel mix ----
      gemm_ffn_kernel<<<gFFN, 512, 0, stream>>>(xn, q1, q2, sl + 4*D, sl + 4*D + FFD, abf, FFD, D);
      gemm_q_kernel<128,0,false,true,true><<<gOC, 512, 0, stream>>>(abf, qoc, sl + 4*D + 2*FFD, nullptr, pk0, D, FFD);
      const float* gnext = (l + 1 < NL) ? (ln1_w + (size_t)(l+1)*D) : ln_out_w;
      rms_radd_kernel<<<M, 256, 0, stream>>>(h, pk0, pk1, gnext, xn);
    }
    gemm_head_kernel<<<gHEAD, 512, 0, stream>>>(xn, embed16, out, V, D);
  } else {
    // ================= FALLBACK: inline-quant path =================
    float* rbuf = rkv;
    float* kbuf = rkv + (size_t)M*D;
    float* vbuf = rkv + 2ull*M*D;
    scales_kernel<<<dim3(ROWS_PER_LAYER, NL), 64, 0, stream>>>(Wr, Wk, Wv, Wo_t, W1, W2, Wo_c, scales);
    const dim3 gD(D/128, M/64);
    const dim3 gF(FFD/128, M/128);
    for (int l = 0; l < NL; ++l) {
      const float* sl = scales + (size_t)l*ROWS_PER_LAYER;
      const float* dcy = decay + (size_t)l*D;
      rms_f16_kernel<<<M, 256, 0, stream>>>(h, ln1_w + (size_t)l*D, xn);
      gemm_bt_kernel<64,1,true,false><<<gD, 256, 0, stream>>>(xn, Wr + (size_t)l*D*D, sl,       nullptr, rbuf, D, D);
      gemm_bt_kernel<64,0,true,false><<<gD, 256, 0, stream>>>(xn, Wk + (size_t)l*D*D, sl + D,   nullptr, kbuf, D, D);
      gemm_bt_kernel<64,0,true,false><<<gD, 256, 0, stream>>>(xn, Wv + (size_t)l*D*D, sl + 2*D, nullptr, vbuf, D, D);
      scan1_kernel<<<gS, 256, 0, stream>>>(kbuf, vbuf, D, dcy, part);
      scan2_kernel<<<gS2, 256, 0, stream>>>(part);
      scan3_kernel<<<gS, 256, 0, stream>>>(rbuf, kbuf, vbuf, D, dcy, part, rsb);
      rms_f16_kernel<<<M, 256, 0, stream>>>(rsb, lnx_w + (size_t)l*D, xn);
      gemm_bt_kernel<64,2,true,false><<<gD, 256, 0, stream>>>(xn, Wo_t + (size_t)l*D*D, sl + 3*D, h, h, D, D);
      rms_f16_kernel<<<M, 256, 0, stream>>>(h, ln2_w + (size_t)l*D, xn);
      gemm_bt_kernel<128,0,true,true><<<gF, 256, 0, stream>>>(xn, W1 + (size_t)l*FFD*D, sl + 4*D,       nullptr, abf, FFD, D);
      gemm_bt_kernel<128,0,true,true><<<gF, 256, 0, stream>>>(xn, W2 + (size_t)l*FFD*D, sl + 4*D + FFD, nullptr, bbf, FFD, D);
      silumul_kernel<<<(M*FFD/4)/256, 256, 0, stream>>>(abf, bbf, abf, M*FFD/4);
      gemm_bt_kernel<64,2,true,false><<<gD, 256, 0, stream>>>(abf, Wo_c + (size_t)l*D*FFD, sl + 4*D + 2*FFD, h, h, D, FFD);
    }
    rms_f16_kernel<<<M, 256, 0, stream>>>(h, ln_out_w, xn);
    gemm_bt_kernel<128,0,false,false><<<dim3(V/128, M/128), 256, 0, stream>>>(xn, embed, nullptr, nullptr, out, V, D);
  }
}

// Round 10
// 1513.338 us; speedup vs baseline: 1.0635x; 1.0635x over previous
//
#include <hip/hip_runtime.h>

typedef _Float16 f16;
typedef _Float16 f16x8 __attribute__((ext_vector_type(8)));
typedef _Float16 f16x4 __attribute__((ext_vector_type(4)));
typedef float f32x4 __attribute__((ext_vector_type(4)));
typedef int i32x4 __attribute__((ext_vector_type(4)));

static constexpr int BB = 2, T = 1024, D = 1024, FFD = 4096, V = 32000, NL = 6;
static constexpr int M = BB * T;                       // 2048 rows
static constexpr int ROWS_PER_LAYER = 4*D + 2*FFD + D; // 13312 scale rows per layer
static constexpr size_t QL = 4ull*D*D + 2ull*FFD*D + (size_t)D*FFD; // 16.78M elems/layer
static constexpr int NT = 64, CT = T / NT;             // scan: 64 chunks x 16 steps
static constexpr int RKV = 3*D;                        // fused rkv row stride

// direct global->LDS, 16B per lane. lds base wave-uniform; HW writes lane i at
// lds + i*16 (m104).
__device__ __forceinline__ void gload16(const f16* g, f16* l) {
  __builtin_amdgcn_global_load_lds(
      (const __attribute__((address_space(1))) void*)g,
      (__attribute__((address_space(3))) void*)l, 16, 0, 0);
}
__device__ __forceinline__ void gload16b(const void* g, void* l) {
  __builtin_amdgcn_global_load_lds(
      (const __attribute__((address_space(1))) void*)g,
      (__attribute__((address_space(3))) void*)l, 16, 0, 0);
}
// counted vmcnt wait: allow the newest stage's N loads to remain in flight.
template<int N> __device__ __forceinline__ void vm_wait() {
  static_assert(N >= 2 && N <= 4, "unsupported vmcnt");
  if constexpr (N == 2) asm volatile("s_waitcnt vmcnt(2)" ::: "memory");
  else if constexpr (N == 3) asm volatile("s_waitcnt vmcnt(3)" ::: "memory");
  else                       asm volatile("s_waitcnt vmcnt(4)" ::: "memory");
}
// ring-phase boundary: all waves' reads of the oldest buffer are complete;
// sched_barrier pins the next stage AFTER the barrier.
__device__ __forceinline__ void ring_barrier() {
  __builtin_amdgcn_s_barrier();
  __builtin_amdgcn_sched_barrier(0);
}

// ---------------------------------------------------------------------------
// Single-pass per-row scale + ternary-quantize to f16 (row held in registers).
// qw layout per layer: [qr(D,D) qk qv qo | q1(FFD,D) q2 | qoc(D,FFD)]
// ---------------------------------------------------------------------------
__global__ __launch_bounds__(256) void quant_kernel(
    const float* __restrict__ Wr, const float* __restrict__ Wk,
    const float* __restrict__ Wv, const float* __restrict__ Wo,
    const float* __restrict__ W1, const float* __restrict__ W2,
    const float* __restrict__ Woc, f16* __restrict__ qw, float* __restrict__ scales)
{
  const int r = blockIdx.x, l = blockIdx.y;
  const float* base; int len; size_t dst;
  if (r < 4*D) {
    const int m = r >> 10, row = r & (D-1);
    const float* Wm = (m==0) ? Wr : (m==1) ? Wk : (m==2) ? Wv : Wo;
    base = Wm + (size_t)l*D*D + (size_t)row*D; len = D;
    dst = (size_t)l*QL + (size_t)m*D*D + (size_t)row*D;
  } else if (r < 4*D + 2*FFD) {
    int row = r - 4*D;
    const int m = row >= FFD; if (m) row -= FFD;
    const float* Wm = m ? W2 : W1;
    base = Wm + (size_t)l*FFD*D + (size_t)row*D; len = D;
    dst = (size_t)l*QL + 4ull*D*D + (size_t)m*FFD*D + (size_t)row*D;
  } else {
    const int row = r - (4*D + 2*FFD);
    base = Woc + (size_t)l*D*FFD + (size_t)row*FFD; len = FFD;
    dst = (size_t)l*QL + 4ull*D*D + 2ull*FFD*D + (size_t)row*FFD;
  }
  const int nv = len >> 10;
  float4 rv[4];
  float sum = 0.f;
  #pragma unroll 4
  for (int i = 0; i < 4; ++i) {
    if (i < nv) {
      rv[i] = reinterpret_cast<const float4*>(base)[threadIdx.x + i*256];
      sum += fabsf(rv[i].x) + fabsf(rv[i].y) + fabsf(rv[i].z) + fabsf(rv[i].w);
    }
  }
  #pragma unroll
  for (int off = 32; off > 0; off >>= 1) sum += __shfl_down(sum, off);
  __shared__ float red[4]; __shared__ float sbc;
  if ((threadIdx.x & 63) == 0) red[threadIdx.x >> 6] = sum;
  __syncthreads();
  if (threadIdx.x == 0) {
    const float s = fmaxf((red[0]+red[1]+red[2]+red[3]) / (float)len, 1e-5f);
    sbc = s;
    scales[(size_t)l*ROWS_PER_LAYER + r] = s;
  }
  __syncthreads();
  const float hs = 0.5f * sbc;
  #pragma unroll 4
  for (int i = 0; i < 4; ++i) {
    if (i < nv) {
      const float4 v = rv[i];
      f16x4 q;
      q[0] = v.x > hs ? (f16)1.f : (v.x < -hs ? (f16)-1.f : (f16)0.f);
      q[1] = v.y > hs ? (f16)1.f : (v.y < -hs ? (f16)-1.f : (f16)0.f);
      q[2] = v.z > hs ? (f16)1.f : (v.z < -hs ? (f16)-1.f : (f16)0.f);
      q[3] = v.w > hs ? (f16)1.f : (v.w < -hs ? (f16)-1.f : (f16)0.f);
      reinterpret_cast<f16x4*>(qw + dst)[threadIdx.x + i*256] = q;
    }
  }
}

// ---------------------------------------------------------------------------
// Per-vocab-row i8 quantize of embed: s = max|row|/127; q = rint(w/s).
// ---------------------------------------------------------------------------
__global__ __launch_bounds__(256) void quant_embed_kernel(
    const float* __restrict__ embed, char* __restrict__ q, float* __restrict__ sw)
{
  const int row = blockIdx.x;
  const float4 v = reinterpret_cast<const float4*>(embed + (size_t)row*D)[threadIdx.x];
  float mx = fmaxf(fmaxf(fabsf(v.x), fabsf(v.y)), fmaxf(fabsf(v.z), fabsf(v.w)));
  #pragma unroll
  for (int off = 32; off > 0; off >>= 1) mx = fmaxf(mx, __shfl_down(mx, off));
  __shared__ float red[4]; __shared__ float sbc;
  if ((threadIdx.x & 63) == 0) red[threadIdx.x >> 6] = mx;
  __syncthreads();
  if (threadIdx.x == 0) {
    const float m = fmaxf(fmaxf(red[0], red[1]), fmaxf(red[2], red[3]));
    const float s = fmaxf(m, 1e-8f) * (1.f/127.f);
    sbc = 1.f / s;
    sw[row] = s;
  }
  __syncthreads();
  const float inv = sbc;
  char4 o;
  o.x = (char)__float2int_rn(v.x * inv); o.y = (char)__float2int_rn(v.y * inv);
  o.z = (char)__float2int_rn(v.z * inv); o.w = (char)__float2int_rn(v.w * inv);
  reinterpret_cast<char4*>(q + (size_t)row*D)[threadIdx.x] = o;
}

// ---------------------------------------------------------------------------
// Per-token-row i8 quantize of f16 activations (head A operand).
// ---------------------------------------------------------------------------
__global__ __launch_bounds__(256) void quant_act_kernel(
    const f16* __restrict__ x, char* __restrict__ q, float* __restrict__ sx)
{
  const int row = blockIdx.x;
  const f16x4 v = reinterpret_cast<const f16x4*>(x + (size_t)row*D)[threadIdx.x];
  const float f0 = (float)v[0], f1 = (float)v[1], f2 = (float)v[2], f3 = (float)v[3];
  float mx = fmaxf(fmaxf(fabsf(f0), fabsf(f1)), fmaxf(fabsf(f2), fabsf(f3)));
  #pragma unroll
  for (int off = 32; off > 0; off >>= 1) mx = fmaxf(mx, __shfl_down(mx, off));
  __shared__ float red[4]; __shared__ float sbc;
  if ((threadIdx.x & 63) == 0) red[threadIdx.x >> 6] = mx;
  __syncthreads();
  if (threadIdx.x == 0) {
    const float m = fmaxf(fmaxf(red[0], red[1]), fmaxf(red[2], red[3]));
    const float s = fmaxf(m, 1e-8f) * (1.f/127.f);
    sbc = 1.f / s;
    sx[row] = s;
  }
  __syncthreads();
  const float inv = sbc;
  char4 o;
  o.x = (char)__float2int_rn(f0 * inv); o.y = (char)__float2int_rn(f1 * inv);
  o.z = (char)__float2int_rn(f2 * inv); o.w = (char)__float2int_rn(f3 * inv);
  reinterpret_cast<char4*>(q + (size_t)row*D)[threadIdx.x] = o;
}

// ---------------------------------------------------------------------------
// h = rmsnorm(embed[idx], ln_in_w), f32 out. One block (256 thr) per row.
// ---------------------------------------------------------------------------
__global__ __launch_bounds__(256) void embed_rms_kernel(
    const int* __restrict__ idx, const float* __restrict__ embed,
    const float* __restrict__ g, float* __restrict__ h)
{
  const int row = blockIdx.x;
  const int tok = idx[row];
  const float4 xv = reinterpret_cast<const float4*>(embed + (size_t)tok*D)[threadIdx.x];
  float ss = xv.x*xv.x + xv.y*xv.y + xv.z*xv.z + xv.w*xv.w;
  #pragma unroll
  for (int off = 32; off > 0; off >>= 1) ss += __shfl_down(ss, off);
  __shared__ float red[4];
  if ((threadIdx.x & 63) == 0) red[threadIdx.x >> 6] = ss;
  __syncthreads();
  const float mean = (red[0]+red[1]+red[2]+red[3]) * (1.f/(float)D);
  const float rn = rsqrtf(mean + 1e-6f);
  const float4 gv = reinterpret_cast<const float4*>(g)[threadIdx.x];
  float4 ov;
  ov.x = xv.x*rn*gv.x; ov.y = xv.y*rn*gv.y; ov.z = xv.z*rn*gv.z; ov.w = xv.w*rn*gv.w;
  reinterpret_cast<float4*>(h + (size_t)row*D)[threadIdx.x] = ov;
}

// ---------------------------------------------------------------------------
// xn = (f16) rmsnorm(x, g). One block (256 thr) per row of 1024.
// ---------------------------------------------------------------------------
__global__ __launch_bounds__(256) void rms_f16_kernel(
    const float* __restrict__ x, const float* __restrict__ g, f16* __restrict__ o)
{
  const int row = blockIdx.x;
  const float4 xv = reinterpret_cast<const float4*>(x + (size_t)row*D)[threadIdx.x];
  float ss = xv.x*xv.x + xv.y*xv.y + xv.z*xv.z + xv.w*xv.w;
  #pragma unroll
  for (int off = 32; off > 0; off >>= 1) ss += __shfl_down(ss, off);
  __shared__ float red[4];
  if ((threadIdx.x & 63) == 0) red[threadIdx.x >> 6] = ss;
  __syncthreads();
  const float mean = (red[0]+red[1]+red[2]+red[3]) * (1.f/(float)D);
  const float rn = rsqrtf(mean + 1e-6f);
  const float4 gv = reinterpret_cast<const float4*>(g)[threadIdx.x];
  f16x4 ov;
  ov[0] = (f16)(xv.x*rn*gv.x); ov[1] = (f16)(xv.y*rn*gv.y);
  ov[2] = (f16)(xv.z*rn*gv.z); ov[3] = (f16)(xv.w*rn*gv.w);
  reinterpret_cast<f16x4*>(o + (size_t)row*D)[threadIdx.x] = ov;
}

// ---------------------------------------------------------------------------
// Fused: h += p0 + p1; xn = (f16) rmsnorm(h, g).
// ---------------------------------------------------------------------------
__global__ __launch_bounds__(256) void rms_radd_kernel(
    float* __restrict__ h, const float* __restrict__ p0,
    const float* __restrict__ p1, const float* __restrict__ g,
    f16* __restrict__ o)
{
  const int row = blockIdx.x;
  const size_t off = (size_t)row*D/4 + threadIdx.x;
  float4 hv = reinterpret_cast<const float4*>(h)[off];
  const float4 a = reinterpret_cast<const float4*>(p0)[off];
  const float4 b = reinterpret_cast<const float4*>(p1)[off];
  hv.x += a.x + b.x; hv.y += a.y + b.y; hv.z += a.z + b.z; hv.w += a.w + b.w;
  reinterpret_cast<float4*>(h)[off] = hv;
  float ss = hv.x*hv.x + hv.y*hv.y + hv.z*hv.z + hv.w*hv.w;
  #pragma unroll
  for (int o2 = 32; o2 > 0; o2 >>= 1) ss += __shfl_down(ss, o2);
  __shared__ float red[4];
  if ((threadIdx.x & 63) == 0) red[threadIdx.x >> 6] = ss;
  __syncthreads();
  const float mean = (red[0]+red[1]+red[2]+red[3]) * (1.f/(float)D);
  const float rn = rsqrtf(mean + 1e-6f);
  const float4 gv = reinterpret_cast<const float4*>(g)[threadIdx.x];
  f16x4 ov;
  ov[0] = (f16)(hv.x*rn*gv.x); ov[1] = (f16)(hv.y*rn*gv.y);
  ov[2] = (f16)(hv.z*rn*gv.z); ov[3] = (f16)(hv.w*rn*gv.w);
  reinterpret_cast<f16x4*>(o + (size_t)row*D)[threadIdx.x] = ov;
}

// ---------------------------------------------------------------------------
// Time-mix recurrence: chunked prefix sum over T.
// ---------------------------------------------------------------------------
__global__ __launch_bounds__(256) void scan1_kernel(
    const float* __restrict__ k, const float* __restrict__ v, int ld,
    const float* __restrict__ decay, float* __restrict__ part)
{
  const int d = blockIdx.x*256 + threadIdx.x;
  const int c = blockIdx.y, b = blockIdx.z;
  const float dec = 1.f / (1.f + expf(-decay[d]));
  const float ldc = logf(fmaxf(dec, 1e-7f));
  float sum = 0.f;
  const int row0 = b*T + c*CT;
  #pragma unroll 4
  for (int t = 0; t < CT; ++t) {
    const size_t i = (size_t)(row0 + t)*ld + d;
    const float scale = expf((float)(c*CT + t) * ldc);
    sum += (k[i] * v[i]) / fmaxf(scale, 1e-10f);
  }
  part[((size_t)b*NT + c)*D + d] = sum;
}

__global__ __launch_bounds__(256) void scan23_kernel(
    const float* __restrict__ r, const float* __restrict__ k,
    const float* __restrict__ v, int ld, const float* __restrict__ decay,
    const float* __restrict__ part, float* __restrict__ rs)
{
  const int d = blockIdx.x*256 + threadIdx.x;
  const int c = blockIdx.y, b = blockIdx.z;
  const float dec = 1.f / (1.f + expf(-decay[d]));
  const float ldc = logf(fmaxf(dec, 1e-7f));
  float cum = 0.f;
  for (int j = 0; j < c; ++j) cum += part[((size_t)b*NT + j)*D + d];
  const int row0 = b*T + c*CT;
  #pragma unroll 4
  for (int t = 0; t < CT; ++t) {
    const size_t i = (size_t)(row0 + t)*ld + d;
    const float scale = expf((float)(c*CT + t) * ldc);
    cum += (k[i] * v[i]) / fmaxf(scale, 1e-10f);
    rs[(size_t)(row0 + t)*D + d] = r[i] * (cum * scale);
  }
}

// fallback-path kernels -------------------------------------------------------
__global__ __launch_bounds__(256) void scan2_kernel(float* __restrict__ part)
{
  const int d = blockIdx.x*256 + threadIdx.x;
  const int b = blockIdx.y;
  float run = 0.f;
  #pragma unroll 8
  for (int c = 0; c < NT; ++c) {
    const size_t i = ((size_t)b*NT + c)*D + d;
    const float t = part[i];
    part[i] = run;
    run += t;
  }
}

__global__ __launch_bounds__(256) void scan3_kernel(
    const float* __restrict__ r, const float* __restrict__ k,
    const float* __restrict__ v, int ld, const float* __restrict__ decay,
    const float* __restrict__ part, float* __restrict__ rs)
{
  const int d = blockIdx.x*256 + threadIdx.x;
  const int c = blockIdx.y, b = blockIdx.z;
  const float dec = 1.f / (1.f + expf(-decay[d]));
  const float ldc = logf(fmaxf(dec, 1e-7f));
  float cum = part[((size_t)b*NT + c)*D + d];
  const int row0 = b*T + c*CT;
  #pragma unroll 4
  for (int t = 0; t < CT; ++t) {
    const size_t i = (size_t)(row0 + t)*ld + d;
    const float scale = expf((float)(c*CT + t) * ldc);
    cum += (k[i] * v[i]) / fmaxf(scale, 1e-10f);
    rs[(size_t)(row0 + t)*D + d] = r[i] * (cum * scale);
  }
}

__global__ __launch_bounds__(256) void silumul_kernel(
    const f16* __restrict__ a, const f16* __restrict__ b, f16* __restrict__ o, int n4)
{
  const int i = blockIdx.x*256 + threadIdx.x;
  if (i >= n4) return;
  const f16x4 av = reinterpret_cast<const f16x4*>(a)[i];
  const f16x4 bv = reinterpret_cast<const f16x4*>(b)[i];
  f16x4 ov;
  #pragma unroll
  for (int j = 0; j < 4; ++j) {
    const float x = (float)av[j];
    ov[j] = (f16)((x / (1.f + expf(-x))) * (float)bv[j]);
  }
  reinterpret_cast<f16x4*>(o)[i] = ov;
}

// ---------------------------------------------------------------------------
// XCD-chunked bijective block swizzle (m204).
// ---------------------------------------------------------------------------
__device__ __forceinline__ int xcd_swizzle(int fid, int nwg) {
  const int q = nwg >> 3, r = nwg & 7, x = fid & 7, o = fid >> 3;
  return (x < r ? x*(q+1) : r*(q+1) + (x-r)*q) + o;
}

// ---------------------------------------------------------------------------
// RING GEMM (round-8 proven): 3-buffer, depth-2 prefetch, counted vmcnt,
// ONE barrier/K-step. out[M,N] = epi(scl[n] * A[M,K] @ Bq[N,K]^T).
// BK=32, linear LDS, BN=128, NW waves. EPI: 0 none, 2 +resid, 3 sigmoid iff
// col<D. SPLITK: gridDim.z pieces write outp + z*M*N.
// ---------------------------------------------------------------------------
template<int BM, int NW, int EPI, bool OUTF16, bool SCALE, bool SPLITK = false>
__global__ __launch_bounds__(NW*64) void gemm_q_kernel(
    const f16* __restrict__ A, const f16* __restrict__ Bq,
    const float* __restrict__ scl, const float* __restrict__ resid,
    void* __restrict__ outp, int N, int K)
{
  constexpr int WN = 2;
  constexpr int WM = NW / WN;
  constexpr int MF = BM / (WM*16);
  constexpr int ACALLS = BM / (16*NW);
  constexpr int BCALLS = 128 / (16*NW);
  constexpr int VCNT = ACALLS + BCALLS;
  __shared__ f16 As[3][BM*32];
  __shared__ f16 Bs[3][128*32];

  const int tid = threadIdx.x;
  const int wave = tid >> 6, lane = tid & 63;
  const int gx = gridDim.x, nwg = gx * gridDim.y;
  const int wg = xcd_swizzle(blockIdx.x + blockIdx.y*gx, nwg);
  const int m0 = (wg % gx) * BM, n0 = (wg / gx) * 128;
  const int lr = lane & 15, kg = lane >> 4;
  const int wm0 = (wave / WN) * (MF*16), wn0 = (wave % WN) * 64;
  const int grow = lane >> 2;
  const int gcol = (lane & 3) * 8;
  const f16* Ab = A  + (size_t)(m0 + grow)*K + gcol;
  const f16* Bb = Bq + (size_t)(n0 + grow)*K + gcol;

  int kbeg = 0, kend = K;
  size_t obase = 0;
  if (SPLITK) {
    const int kc = K / gridDim.z;
    kbeg = blockIdx.z * kc; kend = kbeg + kc;
    obase = (size_t)blockIdx.z * M * (size_t)N;
  }
  const int NKT = (kend - kbeg) / 32;

  auto stage = [&](int buf, int k0) {
    #pragma unroll
    for (int c = 0; c < ACALLS; ++c) {
      const int rb = (c*NW + wave) * 16;
      gload16(Ab + (size_t)rb*K + k0, &As[buf][rb*32]);
    }
    #pragma unroll
    for (int c = 0; c < BCALLS; ++c) {
      const int rb = (c*NW + wave) * 16;
      gload16(Bb + (size_t)rb*K + k0, &Bs[buf][rb*32]);
    }
  };

  f32x4 acc[MF][4] = {};
  stage(0, kbeg);
  stage(1, kbeg + 32);

  int cur = 0;
  for (int t = 0; t < NKT; ++t) {
    vm_wait<VCNT>();
    ring_barrier();
    if (t + 2 < NKT) {
      int nb = cur + 2; if (nb >= 3) nb -= 3;
      stage(nb, kbeg + (t + 2) * 32);
    }
    f16x8 af[MF], bf[4];
    #pragma unroll
    for (int i = 0; i < MF; ++i)
      af[i] = *reinterpret_cast<const f16x8*>(&As[cur][(wm0 + i*16 + lr)*32 + kg*8]);
    #pragma unroll
    for (int j = 0; j < 4; ++j)
      bf[j] = *reinterpret_cast<const f16x8*>(&Bs[cur][(wn0 + j*16 + lr)*32 + kg*8]);
    #pragma unroll
    for (int i = 0; i < MF; ++i)
      #pragma unroll
      for (int j = 0; j < 4; ++j)
        acc[i][j] = __builtin_amdgcn_mfma_f32_16x16x32_f16(af[i], bf[j], acc[i][j], 0, 0, 0);
    ++cur; if (cur == 3) cur = 0;
  }

  // C/D frag layout: col=lane&15, row=(lane>>4)*4+e
  #pragma unroll
  for (int j = 0; j < 4; ++j) {
    const int col = n0 + wn0 + j*16 + lr;
    const float sv = SCALE ? scl[col] : 1.f;
    #pragma unroll
    for (int i = 0; i < MF; ++i) {
      #pragma unroll
      for (int e = 0; e < 4; ++e) {
        const int row = m0 + wm0 + i*16 + kg*4 + e;
        float y = acc[i][j][e] * sv;
        if (EPI == 3 && col < D) y = 1.f / (1.f + expf(-y));
        if (EPI == 2) y += resid[(size_t)row*N + col];
        if (OUTF16) reinterpret_cast<f16*>(outp)[(size_t)row*N + col] = (f16)y;
        else        reinterpret_cast<float*>(outp)[obase + (size_t)row*N + col] = y;
      }
    }
  }
}

// ---------------------------------------------------------------------------
// RING HEAD GEMM, INT8: 128x256 tile, 8 waves, 3-buffer ring, K-step 64.
// A,B i8 (per-row-scaled); LDS row stride 64B; mfma_i32_16x16x64_i8.
// Same 72KB LDS as the f16 128x256 ring -> 2 blocks/CU kept, staged bytes
// per K halved, MFMA instruction count halved.
// out[row,col] = (float)acc * sx[row] * sw[col].
// ---------------------------------------------------------------------------
__global__ __launch_bounds__(512) void gemm_head_i8_kernel(
    const char* __restrict__ A, const char* __restrict__ Bq,
    const float* __restrict__ sx, const float* __restrict__ sw,
    float* __restrict__ out, int N, int K)
{
  constexpr int BM = 128, BN = 256;
  __shared__ __align__(16) char As[3][BM*64];
  __shared__ __align__(16) char Bs[3][BN*64];
  const int tid = threadIdx.x;
  const int wave = tid >> 6, lane = tid & 63;
  const int gx = gridDim.x, nwg = gx * gridDim.y;
  const int wg = xcd_swizzle(blockIdx.x + blockIdx.y*gx, nwg);
  const int m0 = (wg % gx) * BM, n0 = (wg / gx) * BN;
  const int lr = lane & 15, kg = lane >> 4;
  const int wm0 = (wave >> 2) * 64, wn0 = (wave & 3) * 64;
  const int grow = lane >> 2;            // staging: lane -> row in 16-row chunk
  const int gcol = (lane & 3) * 16;      // staging: lane -> 16-i8 col block
  const char* Ab = A  + (size_t)(m0 + grow)*K + gcol;
  const char* Bb = Bq + (size_t)(n0 + grow)*K + gcol;

  auto stage = [&](int buf, int k0) {
    gload16b(Ab + (size_t)(wave*16)*K + k0, &As[buf][(wave*16)*64]);
    gload16b(Bb + (size_t)(wave*16)*K + k0, &Bs[buf][(wave*16)*64]);
    gload16b(Bb + (size_t)((wave+8)*16)*K + k0, &Bs[buf][((wave+8)*16)*64]);
  };

  i32x4 acc[4][4] = {};
  stage(0, 0);
  stage(1, 64);

  const int NKT = K / 64;
  int cur = 0;
  for (int t = 0; t < NKT; ++t) {
    vm_wait<3>();
    ring_barrier();
    if (t + 2 < NKT) {
      int nb = cur + 2; if (nb >= 3) nb -= 3;
      stage(nb, (t + 2) * 64);
    }
    // A frag: lane holds 16 contiguous i8 at k = kg*16 (16x16x64 layout)
    i32x4 af[4], bf[4];
    #pragma unroll
    for (int i = 0; i < 4; ++i)
      af[i] = *reinterpret_cast<const i32x4*>(&As[cur][(wm0 + i*16 + lr)*64 + kg*16]);
    #pragma unroll
    for (int j = 0; j < 4; ++j)
      bf[j] = *reinterpret_cast<const i32x4*>(&Bs[cur][(wn0 + j*16 + lr)*64 + kg*16]);
    #pragma unroll
    for (int i = 0; i < 4; ++i)
      #pragma unroll
      for (int j = 0; j < 4; ++j)
        acc[i][j] = __builtin_amdgcn_mfma_i32_16x16x64_i8(af[i], bf[j], acc[i][j], 0, 0, 0);
    ++cur; if (cur == 3) cur = 0;
  }
  // C/D frag layout: col=lane&15, row=(lane>>4)*4+e (dtype-independent)
  #pragma unroll
  for (int j = 0; j < 4; ++j) {
    const int col = n0 + wn0 + j*16 + lr;
    const float scw = sw[col];
    #pragma unroll
    for (int i = 0; i < 4; ++i) {
      #pragma unroll
      for (int e = 0; e < 4; ++e) {
        const int row = m0 + wm0 + i*16 + kg*4 + e;
        out[(size_t)row*N + col] = (float)acc[i][j][e] * sx[row] * scw;
      }
    }
  }
}

// ---------------------------------------------------------------------------
// RING FUSED FFN GEMM (round-8 proven): 128x128 tile, 8 waves, ring-3.
// g = (f16)( silu(s1[n]*A@B1^T) * (s2[n]*A@B2^T) ).
// ---------------------------------------------------------------------------
__global__ __launch_bounds__(512) void gemm_ffn_kernel(
    const f16* __restrict__ A, const f16* __restrict__ B1, const f16* __restrict__ B2,
    const float* __restrict__ s1, const float* __restrict__ s2,
    f16* __restrict__ outg, int N, int K)
{
  constexpr int BM = 128, BN = 128;
  __shared__ f16 As [3][BM*32];
  __shared__ f16 B1s[3][BN*32];
  __shared__ f16 B2s[3][BN*32];
  const int tid = threadIdx.x;
  const int wave = tid >> 6, lane = tid & 63;
  const int gx = gridDim.x, nwg = gx * gridDim.y;
  const int wg = xcd_swizzle(blockIdx.x + blockIdx.y*gx, nwg);
  const int m0 = (wg % gx) * BM, n0 = (wg / gx) * BN;
  const int lr = lane & 15, kg = lane >> 4;
  const int wm0 = (wave >> 1) * 32, wn0 = (wave & 1) * 64;  // 8 waves: 4M x 2N
  const int grow = lane >> 2, gcol = (lane & 3) * 8;
  const f16* Ab  = A  + (size_t)(m0 + grow)*K + gcol;
  const f16* B1b = B1 + (size_t)(n0 + grow)*K + gcol;
  const f16* B2b = B2 + (size_t)(n0 + grow)*K + gcol;

  auto stage = [&](int buf, int k0) {
    const int rb = wave * 16;
    gload16(Ab  + (size_t)rb*K + k0, &As [buf][rb*32]);
    gload16(B1b + (size_t)rb*K + k0, &B1s[buf][rb*32]);
    gload16(B2b + (size_t)rb*K + k0, &B2s[buf][rb*32]);
  };

  f32x4 aca[2][4] = {};
  f32x4 acb[2][4] = {};
  stage(0, 0);
  stage(1, 32);

  const int NKT = K / 32;
  int cur = 0;
  for (int t = 0; t < NKT; ++t) {
    vm_wait<3>();
    ring_barrier();
    if (t + 2 < NKT) {
      int nb = cur + 2; if (nb >= 3) nb -= 3;
      stage(nb, (t + 2) * 32);
    }
    f16x8 af[2], b1f[4], b2f[4];
    #pragma unroll
    for (int i = 0; i < 2; ++i)
      af[i] = *reinterpret_cast<const f16x8*>(&As[cur][(wm0 + i*16 + lr)*32 + kg*8]);
    #pragma unroll
    for (int j = 0; j < 4; ++j) {
      b1f[j] = *reinterpret_cast<const f16x8*>(&B1s[cur][(wn0 + j*16 + lr)*32 + kg*8]);
      b2f[j] = *reinterpret_cast<const f16x8*>(&B2s[cur][(wn0 + j*16 + lr)*32 + kg*8]);
    }
    #pragma unroll
    for (int i = 0; i < 2; ++i)
      #pragma unroll
      for (int j = 0; j < 4; ++j) {
        aca[i][j] = __builtin_amdgcn_mfma_f32_16x16x32_f16(af[i], b1f[j], aca[i][j], 0, 0, 0);
        acb[i][j] = __builtin_amdgcn_mfma_f32_16x16x32_f16(af[i], b2f[j], acb[i][j], 0, 0, 0);
      }
    ++cur; if (cur == 3) cur = 0;
  }
  #pragma unroll
  for (int j = 0; j < 4; ++j) {
    const int col = n0 + wn0 + j*16 + lr;
    const float sa = s1[col], sb = s2[col];
    #pragma unroll
    for (int i = 0; i < 2; ++i) {
      #pragma unroll
      for (int e = 0; e < 4; ++e) {
        const int row = m0 + wm0 + i*16 + kg*4 + e;
        const float a = aca[i][j][e] * sa;
        const float b = acb[i][j][e] * sb;
        outg[(size_t)row*N + col] = (f16)((a / (1.f + expf(-a))) * b);
      }
    }
  }
}

// ---------------------------------------------------------------------------
// FALLBACK GEMM: inline quantize from f32 weights (used if ws too small).
// ---------------------------------------------------------------------------
__global__ __launch_bounds__(64) void scales_kernel(
    const float* __restrict__ Wr, const float* __restrict__ Wk,
    const float* __restrict__ Wv, const float* __restrict__ Wo,
    const float* __restrict__ W1, const float* __restrict__ W2,
    const float* __restrict__ Woc, float* __restrict__ s)
{
  const int r = blockIdx.x, l = blockIdx.y;
  const float* base; int len;
  if (r < 4*D) {
    const int m = r >> 10, row = r & (D-1);
    const float* Wm = (m==0) ? Wr : (m==1) ? Wk : (m==2) ? Wv : Wo;
    base = Wm + (size_t)l*D*D + (size_t)row*D; len = D;
  } else if (r < 4*D + 2*FFD) {
    int row = r - 4*D;
    const float* Wm = (row < FFD) ? W1 : W2;
    if (row >= FFD) row -= FFD;
    base = Wm + (size_t)l*FFD*D + (size_t)row*D; len = D;
  } else {
    const int row = r - (4*D + 2*FFD);
    base = Woc + (size_t)l*D*FFD + (size_t)row*FFD; len = FFD;
  }
  float sum = 0.f;
  for (int i = threadIdx.x; i < len; i += 64) sum += fabsf(base[i]);
  #pragma unroll
  for (int off = 32; off > 0; off >>= 1) sum += __shfl_down(sum, off);
  if (threadIdx.x == 0)
    s[(size_t)l*ROWS_PER_LAYER + r] = fmaxf(sum / (float)len, 1e-5f);
}

template<int BM, int EPI, bool QUANT, bool OUTF16>
__global__ __launch_bounds__(256) void gemm_bt_kernel(
    const f16* __restrict__ A, const float* __restrict__ Bw,
    const float* __restrict__ scl, const float* __restrict__ resid,
    void* __restrict__ outp, int N, int K)
{
  constexpr int BN = 128, LDT = 40;
  constexpr int MF = (BM == 128) ? 4 : 2;
  __shared__ f16 As[BM*LDT];
  __shared__ f16 Bs[BN*LDT];
  const int tid = threadIdx.x;
  const int m0 = blockIdx.y * BM, n0 = blockIdx.x * BN;
  const int wave = tid >> 6, lane = tid & 63;
  const int lr = lane & 15, kg = lane >> 4;
  const int wm0 = (wave >> 1) * (MF*16), wn0 = (wave & 1) * 64;
  f32x4 acc[MF][4] = {};
  for (int k0 = 0; k0 < K; k0 += 32) {
    #pragma unroll
    for (int c = 0; c < (BM*4)/256; ++c) {
      const int chunk = tid + c*256;
      const int row = chunk >> 2, c8 = (chunk & 3) << 3;
      *reinterpret_cast<f16x8*>(&As[row*LDT + c8]) =
        *reinterpret_cast<const f16x8*>(A + (size_t)(m0+row)*K + k0 + c8);
    }
    #pragma unroll
    for (int c = 0; c < 2; ++c) {
      const int chunk = tid + c*256;
      const int row = chunk >> 2, c8 = (chunk & 3) << 3;
      const float* bp = Bw + (size_t)(n0+row)*K + k0 + c8;
      const float4 f0 = *reinterpret_cast<const float4*>(bp);
      const float4 f1 = *reinterpret_cast<const float4*>(bp + 4);
      const float wv[8] = {f0.x,f0.y,f0.z,f0.w,f1.x,f1.y,f1.z,f1.w};
      f16x8 qv;
      if (QUANT) {
        const float hs = 0.5f * scl[n0+row];
        #pragma unroll
        for (int j = 0; j < 8; ++j)
          qv[j] = wv[j] > hs ? (f16)1.f : (wv[j] < -hs ? (f16)(-1.f) : (f16)0.f);
      } else {
        #pragma unroll
        for (int j = 0; j < 8; ++j) qv[j] = (f16)wv[j];
      }
      *reinterpret_cast<f16x8*>(&Bs[row*LDT + c8]) = qv;
    }
    __syncthreads();
    f16x8 af[MF], bf[4];
    #pragma unroll
    for (int i = 0; i < MF; ++i)
      af[i] = *reinterpret_cast<const f16x8*>(&As[(wm0 + i*16 + lr)*LDT + kg*8]);
    #pragma unroll
    for (int j = 0; j < 4; ++j)
      bf[j] = *reinterpret_cast<const f16x8*>(&Bs[(wn0 + j*16 + lr)*LDT + kg*8]);
    #pragma unroll
    for (int i = 0; i < MF; ++i)
      #pragma unroll
      for (int j = 0; j < 4; ++j)
        acc[i][j] = __builtin_amdgcn_mfma_f32_16x16x32_f16(af[i], bf[j], acc[i][j], 0, 0, 0);
    __syncthreads();
  }
  #pragma unroll
  for (int j = 0; j < 4; ++j) {
    const int col = n0 + wn0 + j*16 + lr;
    const float sv = QUANT ? scl[col] : 1.f;
    #pragma unroll
    for (int i = 0; i < MF; ++i) {
      #pragma unroll
      for (int e = 0; e < 4; ++e) {
        const int row = m0 + wm0 + i*16 + kg*4 + e;
        float y = acc[i][j][e] * sv;
        if (EPI == 1) y = 1.f / (1.f + expf(-y));
        if (EPI == 2) y += resid[(size_t)row*N + col];
        if (OUTF16) reinterpret_cast<f16*>(outp)[(size_t)row*N + col] = (f16)y;
        else        reinterpret_cast<float*>(outp)[(size_t)row*N + col] = y;
      }
    }
  }
}

// ---------------------------------------------------------------------------
extern "C" void kernel_launch(void* const* d_in, const int* in_sizes, int n_in,
                              void* d_out, int out_size, void* d_ws, size_t ws_size,
                              hipStream_t stream)
{
  (void)in_sizes; (void)n_in; (void)out_size;
  const int*   idx      = (const int*)  d_in[0];
  const float* embed    = (const float*)d_in[1];
  const float* ln_in_w  = (const float*)d_in[2];
  const float* ln1_w    = (const float*)d_in[3];
  const float* Wr       = (const float*)d_in[4];
  const float* Wk       = (const float*)d_in[5];
  const float* Wv       = (const float*)d_in[6];
  const float* Wo_t     = (const float*)d_in[7];
  const float* decay    = (const float*)d_in[8];
  const float* lnx_w    = (const float*)d_in[9];
  const float* ln2_w    = (const float*)d_in[10];
  const float* W1       = (const float*)d_in[11];
  const float* W2       = (const float*)d_in[12];
  const float* Wo_c     = (const float*)d_in[13];
  const float* ln_out_w = (const float*)d_in[14];
  float* out = (float*)d_out;

  char* p = (char*)d_ws;
  auto alloc = [&](size_t bytes) { void* q = (void*)p; p += (bytes + 255) & ~(size_t)255; return q; };
  float* h      = (float*)alloc((size_t)M*D*sizeof(float));
  f16*   xn     = (f16*)  alloc((size_t)M*D*sizeof(f16));
  float* rkv    = (float*)alloc((size_t)M*RKV*sizeof(float));   // r|k|v; reused as split-K partials
  float* rsb    = (float*)alloc((size_t)M*D*sizeof(float));
  f16*   abf    = (f16*)  alloc((size_t)M*FFD*sizeof(f16));
  f16*   bbf    = (f16*)  alloc((size_t)M*FFD*sizeof(f16));     // fallback only
  float* scales = (float*)alloc((size_t)NL*ROWS_PER_LAYER*sizeof(float));
  float* part   = (float*)alloc((size_t)BB*NT*D*sizeof(float));
  const size_t base_need = (size_t)(p - (char*)d_ws);
  const size_t fast_need = base_need + (NL*QL*sizeof(f16) + 256)
      + ((size_t)V*D + 256) + (V*sizeof(float) + 256)
      + ((size_t)M*D + 256) + (M*sizeof(float) + 256);

  embed_rms_kernel<<<M, 256, 0, stream>>>(idx, embed, ln_in_w, h);

  const dim3 gS(D/256, NT, BB);   // scan1/scan23: 512 blocks
  const dim3 gS2(D/256, BB);      // scan2 (fallback): 8 blocks

  if (ws_size >= fast_need) {
    // ================= FAST PATH: pre-quantized weights =================
    f16*   qw   = (f16*)  alloc(NL*QL*sizeof(f16));
    char*  emb8 = (char*) alloc((size_t)V*D);
    float* sw   = (float*)alloc((size_t)V*sizeof(float));
    char*  xn8  = (char*) alloc((size_t)M*D);
    float* sx   = (float*)alloc((size_t)M*sizeof(float));
    quant_kernel<<<dim3(ROWS_PER_LAYER, NL), 256, 0, stream>>>(Wr, Wk, Wv, Wo_t, W1, W2, Wo_c, qw, scales);
    quant_embed_kernel<<<V, 256, 0, stream>>>(embed, emb8, sw);

    const dim3 gRKV(M/128, RKV/128);     // 16 x 24 = 384 blocks, 8 waves
    const dim3 gO(M/64, D/128);          // 32 x 8  = 256 blocks, 4 waves
    const dim3 gOC(M/64, D/128, 2);      // 512 blocks (split-K x2)
    const dim3 gFFN(M/128, FFD/128);     // 16 x 32 = 512 blocks, 8 waves
    const dim3 gHEAD(M/128, V/256);      // 16 x 125 = 2000 blocks, 8 waves

    rms_f16_kernel<<<M, 256, 0, stream>>>(h, ln1_w, xn);   // first layer's ln1
    for (int l = 0; l < NL; ++l) {
      const float* sl = scales + (size_t)l*ROWS_PER_LAYER;
      const f16* qb = qw + (size_t)l*QL;
      const f16 *qrkv = qb, *qo = qb + 3ull*D*D;
      const f16 *q1 = qb + 4ull*D*D, *q2 = qb + 4ull*D*D + (size_t)FFD*D;
      const f16 *qoc = qb + 4ull*D*D + 2ull*(size_t)FFD*D;
      const float* dcy = decay + (size_t)l*D;
      // ---- time mix ----
      gemm_q_kernel<128,8,3,false,true><<<gRKV, 512, 0, stream>>>(xn, qrkv, sl, nullptr, rkv, RKV, D);
      scan1_kernel<<<gS, 256, 0, stream>>>(rkv + D, rkv + 2*D, RKV, dcy, part);
      scan23_kernel<<<gS, 256, 0, stream>>>(rkv, rkv + D, rkv + 2*D, RKV, dcy, part, rsb);
      rms_f16_kernel<<<M, 256, 0, stream>>>(rsb, lnx_w + (size_t)l*D, xn);
      gemm_q_kernel<64,4,2,false,true><<<gO, 256, 0, stream>>>(xn, qo, sl + 3*D, h, h, D, D);
      // ---- channel mix ----
      rms_f16_kernel<<<M, 256, 0, stream>>>(h, ln2_w + (size_t)l*D, xn);
      gemm_ffn_kernel<<<gFFN, 512, 0, stream>>>(xn, q1, q2, sl + 4*D, sl + 4*D + FFD, abf, FFD, D);
      gemm_q_kernel<64,4,0,false,true,true><<<gOC, 256, 0, stream>>>(abf, qoc, sl + 4*D + 2*FFD, nullptr, rkv, D, FFD);
      const float* gnext = (l + 1 < NL) ? (ln1_w + (size_t)(l+1)*D) : ln_out_w;
      rms_radd_kernel<<<M, 256, 0, stream>>>(h, rkv, rkv + (size_t)M*D, gnext, xn);
    }
    // ---- weight-tied head: i8 x i8 ----
    quant_act_kernel<<<M, 256, 0, stream>>>(xn, xn8, sx);
    gemm_head_i8_kernel<<<gHEAD, 512, 0, stream>>>(xn8, emb8, sx, sw, out, V, D);
  } else {
    // ================= FALLBACK: inline-quant path =================
    float* rbuf = rkv;
    float* kbuf = rkv + (size_t)M*D;
    float* vbuf = rkv + 2ull*M*D;
    scales_kernel<<<dim3(ROWS_PER_LAYER, NL), 64, 0, stream>>>(Wr, Wk, Wv, Wo_t, W1, W2, Wo_c, scales);
    const dim3 gD(D/128, M/64);
    const dim3 gF(FFD/128, M/128);
    for (int l = 0; l < NL; ++l) {
      const float* sl = scales + (size_t)l*ROWS_PER_LAYER;
      const float* dcy = decay + (size_t)l*D;
      rms_f16_kernel<<<M, 256, 0, stream>>>(h, ln1_w + (size_t)l*D, xn);
      gemm_bt_kernel<64,1,true,false><<<gD, 256, 0, stream>>>(xn, Wr + (size_t)l*D*D, sl,       nullptr, rbuf, D, D);
      gemm_bt_kernel<64,0,true,false><<<gD, 256, 0, stream>>>(xn, Wk + (size_t)l*D*D, sl + D,   nullptr, kbuf, D, D);
      gemm_bt_kernel<64,0,true,false><<<gD, 256, 0, stream>>>(xn, Wv + (size_t)l*D*D, sl + 2*D, nullptr, vbuf, D, D);
      scan1_kernel<<<gS, 256, 0, stream>>>(kbuf, vbuf, D, dcy, part);
      scan2_kernel<<<gS2, 256, 0, stream>>>(part);
      scan3_kernel<<<gS, 256, 0, stream>>>(rbuf, kbuf, vbuf, D, dcy, part, rsb);
      rms_f16_kernel<<<M, 256, 0, stream>>>(rsb, lnx_w + (size_t)l*D, xn);
      gemm_bt_kernel<64,2,true,false><<<gD, 256, 0, stream>>>(xn, Wo_t + (size_t)l*D*D, sl + 3*D, h, h, D, D);
      rms_f16_kernel<<<M, 256, 0, stream>>>(h, ln2_w + (size_t)l*D, xn);
      gemm_bt_kernel<128,0,true,true><<<gF, 256, 0, stream>>>(xn, W1 + (size_t)l*FFD*D, sl + 4*D,       nullptr, abf, FFD, D);
      gemm_bt_kernel<128,0,true,true><<<gF, 256, 0, stream>>>(xn, W2 + (size_t)l*FFD*D, sl + 4*D + FFD, nullptr, bbf, FFD, D);
      silumul_kernel<<<(M*FFD/4)/256, 256, 0, stream>>>(abf, bbf, abf, M*FFD/4);
      gemm_bt_kernel<64,2,true,false><<<gD, 256, 0, stream>>>(abf, Wo_c + (size_t)l*D*FFD, sl + 4*D + 2*FFD, h, h, D, FFD);
    }
    rms_f16_kernel<<<M, 256, 0, stream>>>(h, ln_out_w, xn);
    gemm_bt_kernel<128,0,false,false><<<dim3(V/128, M/128), 256, 0, stream>>>(xn, embed, nullptr, nullptr, out, V, D);
  }
}

// Round 11
// 1189.937 us; speedup vs baseline: 1.3525x; 1.2718x over previous
//
#include <hip/hip_runtime.h>

typedef _Float16 f16;
typedef _Float16 f16x8 __attribute__((ext_vector_type(8)));
typedef _Float16 f16x4 __attribute__((ext_vector_type(4)));
typedef float f32x4 __attribute__((ext_vector_type(4)));
typedef int i32x4 __attribute__((ext_vector_type(4)));

static constexpr int BB = 2, T = 1024, D = 1024, FFD = 4096, V = 32000, NL = 6;
static constexpr int M = BB * T;                       // 2048 rows
static constexpr int ROWS_PER_LAYER = 4*D + 2*FFD + D; // 13312 scale rows per layer
static constexpr size_t QL = 4ull*D*D + 2ull*FFD*D + (size_t)D*FFD; // 16.78M elems/layer
static constexpr int NT = 64, CT = T / NT;             // scan: 64 chunks x 16 steps
static constexpr int RKV = 3*D;                        // fused rkv row stride

// direct global->LDS, 16B per lane. lds base wave-uniform; HW writes lane i at
// lds + i*16 (m104).
__device__ __forceinline__ void gload16(const f16* g, f16* l) {
  __builtin_amdgcn_global_load_lds(
      (const __attribute__((address_space(1))) void*)g,
      (__attribute__((address_space(3))) void*)l, 16, 0, 0);
}
__device__ __forceinline__ void gload16b(const void* g, void* l) {
  __builtin_amdgcn_global_load_lds(
      (const __attribute__((address_space(1))) void*)g,
      (__attribute__((address_space(3))) void*)l, 16, 0, 0);
}
// counted vmcnt wait: allow the newest stage's N loads to remain in flight.
template<int N> __device__ __forceinline__ void vm_wait() {
  static_assert(N >= 2 && N <= 4, "unsupported vmcnt");
  if constexpr (N == 2) asm volatile("s_waitcnt vmcnt(2)" ::: "memory");
  else if constexpr (N == 3) asm volatile("s_waitcnt vmcnt(3)" ::: "memory");
  else                       asm volatile("s_waitcnt vmcnt(4)" ::: "memory");
}
// ring-phase boundary: all waves' reads of the oldest buffer are complete;
// sched_barrier pins the next stage AFTER the barrier.
__device__ __forceinline__ void ring_barrier() {
  __builtin_amdgcn_s_barrier();
  __builtin_amdgcn_sched_barrier(0);
}

// ---------------------------------------------------------------------------
// Single-pass per-row scale + ternary-quantize to i8 (EXACT: w_q in {-1,0,1}).
// qw layout per layer: [qr(D,D) qk qv qo | q1(FFD,D) q2 | qoc(D,FFD)]
// ---------------------------------------------------------------------------
__global__ __launch_bounds__(256) void quant_kernel(
    const float* __restrict__ Wr, const float* __restrict__ Wk,
    const float* __restrict__ Wv, const float* __restrict__ Wo,
    const float* __restrict__ W1, const float* __restrict__ W2,
    const float* __restrict__ Woc, char* __restrict__ qw, float* __restrict__ scales)
{
  const int r = blockIdx.x, l = blockIdx.y;
  const float* base; int len; size_t dst;
  if (r < 4*D) {
    const int m = r >> 10, row = r & (D-1);
    const float* Wm = (m==0) ? Wr : (m==1) ? Wk : (m==2) ? Wv : Wo;
    base = Wm + (size_t)l*D*D + (size_t)row*D; len = D;
    dst = (size_t)l*QL + (size_t)m*D*D + (size_t)row*D;
  } else if (r < 4*D + 2*FFD) {
    int row = r - 4*D;
    const int m = row >= FFD; if (m) row -= FFD;
    const float* Wm = m ? W2 : W1;
    base = Wm + (size_t)l*FFD*D + (size_t)row*D; len = D;
    dst = (size_t)l*QL + 4ull*D*D + (size_t)m*FFD*D + (size_t)row*D;
  } else {
    const int row = r - (4*D + 2*FFD);
    base = Woc + (size_t)l*D*FFD + (size_t)row*FFD; len = FFD;
    dst = (size_t)l*QL + 4ull*D*D + 2ull*FFD*D + (size_t)row*FFD;
  }
  const int nv = len >> 10;        // float4s per thread: 1 (len=1024) or 4 (4096)
  float4 rv[4];
  float sum = 0.f;
  #pragma unroll 4
  for (int i = 0; i < 4; ++i) {
    if (i < nv) {
      rv[i] = reinterpret_cast<const float4*>(base)[threadIdx.x + i*256];
      sum += fabsf(rv[i].x) + fabsf(rv[i].y) + fabsf(rv[i].z) + fabsf(rv[i].w);
    }
  }
  #pragma unroll
  for (int off = 32; off > 0; off >>= 1) sum += __shfl_down(sum, off);
  __shared__ float red[4]; __shared__ float sbc;
  if ((threadIdx.x & 63) == 0) red[threadIdx.x >> 6] = sum;
  __syncthreads();
  if (threadIdx.x == 0) {
    const float s = fmaxf((red[0]+red[1]+red[2]+red[3]) / (float)len, 1e-5f);
    sbc = s;
    scales[(size_t)l*ROWS_PER_LAYER + r] = s;
  }
  __syncthreads();
  const float hs = 0.5f * sbc;
  #pragma unroll 4
  for (int i = 0; i < 4; ++i) {
    if (i < nv) {
      const float4 v = rv[i];
      char4 q;
      q.x = v.x > hs ? 1 : (v.x < -hs ? -1 : 0);
      q.y = v.y > hs ? 1 : (v.y < -hs ? -1 : 0);
      q.z = v.z > hs ? 1 : (v.z < -hs ? -1 : 0);
      q.w = v.w > hs ? 1 : (v.w < -hs ? -1 : 0);
      reinterpret_cast<char4*>(qw + dst)[threadIdx.x + i*256] = q;
    }
  }
}

// ---------------------------------------------------------------------------
// Per-vocab-row i8 quantize of embed: s = max|row|/127; q = rint(w/s).
// ---------------------------------------------------------------------------
__global__ __launch_bounds__(256) void quant_embed_kernel(
    const float* __restrict__ embed, char* __restrict__ q, float* __restrict__ sw)
{
  const int row = blockIdx.x;
  const float4 v = reinterpret_cast<const float4*>(embed + (size_t)row*D)[threadIdx.x];
  float mx = fmaxf(fmaxf(fabsf(v.x), fabsf(v.y)), fmaxf(fabsf(v.z), fabsf(v.w)));
  #pragma unroll
  for (int off = 32; off > 0; off >>= 1) mx = fmaxf(mx, __shfl_down(mx, off));
  __shared__ float red[4]; __shared__ float sbc;
  if ((threadIdx.x & 63) == 0) red[threadIdx.x >> 6] = mx;
  __syncthreads();
  if (threadIdx.x == 0) {
    const float m = fmaxf(fmaxf(red[0], red[1]), fmaxf(red[2], red[3]));
    const float s = fmaxf(m, 1e-8f) * (1.f/127.f);
    sbc = 1.f / s;
    sw[row] = s;
  }
  __syncthreads();
  const float inv = sbc;
  char4 o;
  o.x = (char)__float2int_rn(v.x * inv); o.y = (char)__float2int_rn(v.y * inv);
  o.z = (char)__float2int_rn(v.z * inv); o.w = (char)__float2int_rn(v.w * inv);
  reinterpret_cast<char4*>(q + (size_t)row*D)[threadIdx.x] = o;
}

// ---------------------------------------------------------------------------
// h = rmsnorm(embed[idx], ln_in_w), f32 out. One block (256 thr) per row.
// ---------------------------------------------------------------------------
__global__ __launch_bounds__(256) void embed_rms_kernel(
    const int* __restrict__ idx, const float* __restrict__ embed,
    const float* __restrict__ g, float* __restrict__ h)
{
  const int row = blockIdx.x;
  const int tok = idx[row];
  const float4 xv = reinterpret_cast<const float4*>(embed + (size_t)tok*D)[threadIdx.x];
  float ss = xv.x*xv.x + xv.y*xv.y + xv.z*xv.z + xv.w*xv.w;
  #pragma unroll
  for (int off = 32; off > 0; off >>= 1) ss += __shfl_down(ss, off);
  __shared__ float red[4];
  if ((threadIdx.x & 63) == 0) red[threadIdx.x >> 6] = ss;
  __syncthreads();
  const float mean = (red[0]+red[1]+red[2]+red[3]) * (1.f/(float)D);
  const float rn = rsqrtf(mean + 1e-6f);
  const float4 gv = reinterpret_cast<const float4*>(g)[threadIdx.x];
  float4 ov;
  ov.x = xv.x*rn*gv.x; ov.y = xv.y*rn*gv.y; ov.z = xv.z*rn*gv.z; ov.w = xv.w*rn*gv.w;
  reinterpret_cast<float4*>(h + (size_t)row*D)[threadIdx.x] = ov;
}

// ---------------------------------------------------------------------------
// xn8 = i8-quantized rmsnorm(x, g) with per-row scale sx (fused, one pass).
// ss and row-max computed in the same shuffle reduction.
// ---------------------------------------------------------------------------
__global__ __launch_bounds__(256) void rms_i8_kernel(
    const float* __restrict__ x, const float* __restrict__ g,
    char* __restrict__ q, float* __restrict__ sx)
{
  const int row = blockIdx.x;
  const float4 xv = reinterpret_cast<const float4*>(x + (size_t)row*D)[threadIdx.x];
  const float4 gv = reinterpret_cast<const float4*>(g)[threadIdx.x];
  float4 pv;
  pv.x = xv.x*gv.x; pv.y = xv.y*gv.y; pv.z = xv.z*gv.z; pv.w = xv.w*gv.w;
  float ss = xv.x*xv.x + xv.y*xv.y + xv.z*xv.z + xv.w*xv.w;
  float mg = fmaxf(fmaxf(fabsf(pv.x), fabsf(pv.y)), fmaxf(fabsf(pv.z), fabsf(pv.w)));
  #pragma unroll
  for (int off = 32; off > 0; off >>= 1) {
    ss += __shfl_down(ss, off);
    mg = fmaxf(mg, __shfl_down(mg, off));
  }
  __shared__ float reds[4], redm[4]; __shared__ float sbc;
  if ((threadIdx.x & 63) == 0) { reds[threadIdx.x >> 6] = ss; redm[threadIdx.x >> 6] = mg; }
  __syncthreads();
  if (threadIdx.x == 0) {
    const float mean = (reds[0]+reds[1]+reds[2]+reds[3]) * (1.f/(float)D);
    const float rn = rsqrtf(mean + 1e-6f);
    const float vmax = rn * fmaxf(fmaxf(redm[0], redm[1]), fmaxf(redm[2], redm[3]));
    const float s = fmaxf(vmax, 1e-8f) * (1.f/127.f);
    sx[row] = s;
    sbc = rn / s;
  }
  __syncthreads();
  const float f = sbc;
  char4 o;
  o.x = (char)__float2int_rn(pv.x * f); o.y = (char)__float2int_rn(pv.y * f);
  o.z = (char)__float2int_rn(pv.z * f); o.w = (char)__float2int_rn(pv.w * f);
  reinterpret_cast<char4*>(q + (size_t)row*D)[threadIdx.x] = o;
}

// ---------------------------------------------------------------------------
// Fused: h += p0 + p1; xn8 = i8 rmsnorm(h, g) + per-row scale sx.
// ---------------------------------------------------------------------------
__global__ __launch_bounds__(256) void rms_radd_i8_kernel(
    float* __restrict__ h, const float* __restrict__ p0,
    const float* __restrict__ p1, const float* __restrict__ g,
    char* __restrict__ q, float* __restrict__ sx)
{
  const int row = blockIdx.x;
  const size_t off = (size_t)row*D/4 + threadIdx.x;
  float4 hv = reinterpret_cast<const float4*>(h)[off];
  const float4 a = reinterpret_cast<const float4*>(p0)[off];
  const float4 b = reinterpret_cast<const float4*>(p1)[off];
  hv.x += a.x + b.x; hv.y += a.y + b.y; hv.z += a.z + b.z; hv.w += a.w + b.w;
  reinterpret_cast<float4*>(h)[off] = hv;
  const float4 gv = reinterpret_cast<const float4*>(g)[threadIdx.x];
  float4 pv;
  pv.x = hv.x*gv.x; pv.y = hv.y*gv.y; pv.z = hv.z*gv.z; pv.w = hv.w*gv.w;
  float ss = hv.x*hv.x + hv.y*hv.y + hv.z*hv.z + hv.w*hv.w;
  float mg = fmaxf(fmaxf(fabsf(pv.x), fabsf(pv.y)), fmaxf(fabsf(pv.z), fabsf(pv.w)));
  #pragma unroll
  for (int o2 = 32; o2 > 0; o2 >>= 1) {
    ss += __shfl_down(ss, o2);
    mg = fmaxf(mg, __shfl_down(mg, o2));
  }
  __shared__ float reds[4], redm[4]; __shared__ float sbc;
  if ((threadIdx.x & 63) == 0) { reds[threadIdx.x >> 6] = ss; redm[threadIdx.x >> 6] = mg; }
  __syncthreads();
  if (threadIdx.x == 0) {
    const float mean = (reds[0]+reds[1]+reds[2]+reds[3]) * (1.f/(float)D);
    const float rn = rsqrtf(mean + 1e-6f);
    const float vmax = rn * fmaxf(fmaxf(redm[0], redm[1]), fmaxf(redm[2], redm[3]));
    const float s = fmaxf(vmax, 1e-8f) * (1.f/127.f);
    sx[row] = s;
    sbc = rn / s;
  }
  __syncthreads();
  const float f = sbc;
  char4 o;
  o.x = (char)__float2int_rn(pv.x * f); o.y = (char)__float2int_rn(pv.y * f);
  o.z = (char)__float2int_rn(pv.z * f); o.w = (char)__float2int_rn(pv.w * f);
  reinterpret_cast<char4*>(q + (size_t)row*D)[threadIdx.x] = o;
}

// ---------------------------------------------------------------------------
// Per-row (len FFD=4096) i8 quantize of the FFN intermediate (f16 in).
// ---------------------------------------------------------------------------
__global__ __launch_bounds__(256) void quant_ffn_kernel(
    const f16* __restrict__ a, char* __restrict__ q, float* __restrict__ s)
{
  const int row = blockIdx.x;
  const size_t base = (size_t)row*(FFD/4);
  f16x4 v[4];
  float mx = 0.f;
  #pragma unroll
  for (int i = 0; i < 4; ++i) {
    v[i] = reinterpret_cast<const f16x4*>(a)[base + threadIdx.x + i*256];
    #pragma unroll
    for (int j = 0; j < 4; ++j) mx = fmaxf(mx, fabsf((float)v[i][j]));
  }
  #pragma unroll
  for (int off = 32; off > 0; off >>= 1) mx = fmaxf(mx, __shfl_down(mx, off));
  __shared__ float red[4]; __shared__ float sbc;
  if ((threadIdx.x & 63) == 0) red[threadIdx.x >> 6] = mx;
  __syncthreads();
  if (threadIdx.x == 0) {
    const float m = fmaxf(fmaxf(red[0], red[1]), fmaxf(red[2], red[3]));
    const float sr = fmaxf(m, 1e-8f) * (1.f/127.f);
    s[row] = sr;
    sbc = 1.f / sr;
  }
  __syncthreads();
  const float inv = sbc;
  #pragma unroll
  for (int i = 0; i < 4; ++i) {
    char4 o;
    o.x = (char)__float2int_rn((float)v[i][0] * inv);
    o.y = (char)__float2int_rn((float)v[i][1] * inv);
    o.z = (char)__float2int_rn((float)v[i][2] * inv);
    o.w = (char)__float2int_rn((float)v[i][3] * inv);
    reinterpret_cast<char4*>(q)[base + threadIdx.x + i*256] = o;
  }
}

// ---------------------------------------------------------------------------
// Time-mix recurrence: chunked prefix sum over T.
// ---------------------------------------------------------------------------
__global__ __launch_bounds__(256) void scan1_kernel(
    const float* __restrict__ k, const float* __restrict__ v, int ld,
    const float* __restrict__ decay, float* __restrict__ part)
{
  const int d = blockIdx.x*256 + threadIdx.x;
  const int c = blockIdx.y, b = blockIdx.z;
  const float dec = 1.f / (1.f + expf(-decay[d]));
  const float ldc = logf(fmaxf(dec, 1e-7f));
  float sum = 0.f;
  const int row0 = b*T + c*CT;
  #pragma unroll 4
  for (int t = 0; t < CT; ++t) {
    const size_t i = (size_t)(row0 + t)*ld + d;
    const float scale = expf((float)(c*CT + t) * ldc);
    sum += (k[i] * v[i]) / fmaxf(scale, 1e-10f);
  }
  part[((size_t)b*NT + c)*D + d] = sum;
}

__global__ __launch_bounds__(256) void scan23_kernel(
    const float* __restrict__ r, const float* __restrict__ k,
    const float* __restrict__ v, int ld, const float* __restrict__ decay,
    const float* __restrict__ part, float* __restrict__ rs)
{
  const int d = blockIdx.x*256 + threadIdx.x;
  const int c = blockIdx.y, b = blockIdx.z;
  const float dec = 1.f / (1.f + expf(-decay[d]));
  const float ldc = logf(fmaxf(dec, 1e-7f));
  float cum = 0.f;
  for (int j = 0; j < c; ++j) cum += part[((size_t)b*NT + j)*D + d];
  const int row0 = b*T + c*CT;
  #pragma unroll 4
  for (int t = 0; t < CT; ++t) {
    const size_t i = (size_t)(row0 + t)*ld + d;
    const float scale = expf((float)(c*CT + t) * ldc);
    cum += (k[i] * v[i]) / fmaxf(scale, 1e-10f);
    rs[(size_t)(row0 + t)*D + d] = r[i] * (cum * scale);
  }
}

// fallback-path kernels -------------------------------------------------------
__global__ __launch_bounds__(256) void rms_f16_kernel(
    const float* __restrict__ x, const float* __restrict__ g, f16* __restrict__ o)
{
  const int row = blockIdx.x;
  const float4 xv = reinterpret_cast<const float4*>(x + (size_t)row*D)[threadIdx.x];
  float ss = xv.x*xv.x + xv.y*xv.y + xv.z*xv.z + xv.w*xv.w;
  #pragma unroll
  for (int off = 32; off > 0; off >>= 1) ss += __shfl_down(ss, off);
  __shared__ float red[4];
  if ((threadIdx.x & 63) == 0) red[threadIdx.x >> 6] = ss;
  __syncthreads();
  const float mean = (red[0]+red[1]+red[2]+red[3]) * (1.f/(float)D);
  const float rn = rsqrtf(mean + 1e-6f);
  const float4 gv = reinterpret_cast<const float4*>(g)[threadIdx.x];
  f16x4 ov;
  ov[0] = (f16)(xv.x*rn*gv.x); ov[1] = (f16)(xv.y*rn*gv.y);
  ov[2] = (f16)(xv.z*rn*gv.z); ov[3] = (f16)(xv.w*rn*gv.w);
  reinterpret_cast<f16x4*>(o + (size_t)row*D)[threadIdx.x] = ov;
}

__global__ __launch_bounds__(256) void scan2_kernel(float* __restrict__ part)
{
  const int d = blockIdx.x*256 + threadIdx.x;
  const int b = blockIdx.y;
  float run = 0.f;
  #pragma unroll 8
  for (int c = 0; c < NT; ++c) {
    const size_t i = ((size_t)b*NT + c)*D + d;
    const float t = part[i];
    part[i] = run;
    run += t;
  }
}

__global__ __launch_bounds__(256) void scan3_kernel(
    const float* __restrict__ r, const float* __restrict__ k,
    const float* __restrict__ v, int ld, const float* __restrict__ decay,
    const float* __restrict__ part, float* __restrict__ rs)
{
  const int d = blockIdx.x*256 + threadIdx.x;
  const int c = blockIdx.y, b = blockIdx.z;
  const float dec = 1.f / (1.f + expf(-decay[d]));
  const float ldc = logf(fmaxf(dec, 1e-7f));
  float cum = part[((size_t)b*NT + c)*D + d];
  const int row0 = b*T + c*CT;
  #pragma unroll 4
  for (int t = 0; t < CT; ++t) {
    const size_t i = (size_t)(row0 + t)*ld + d;
    const float scale = expf((float)(c*CT + t) * ldc);
    cum += (k[i] * v[i]) / fmaxf(scale, 1e-10f);
    rs[(size_t)(row0 + t)*D + d] = r[i] * (cum * scale);
  }
}

__global__ __launch_bounds__(256) void silumul_kernel(
    const f16* __restrict__ a, const f16* __restrict__ b, f16* __restrict__ o, int n4)
{
  const int i = blockIdx.x*256 + threadIdx.x;
  if (i >= n4) return;
  const f16x4 av = reinterpret_cast<const f16x4*>(a)[i];
  const f16x4 bv = reinterpret_cast<const f16x4*>(b)[i];
  f16x4 ov;
  #pragma unroll
  for (int j = 0; j < 4; ++j) {
    const float x = (float)av[j];
    ov[j] = (f16)((x / (1.f + expf(-x))) * (float)bv[j]);
  }
  reinterpret_cast<f16x4*>(o)[i] = ov;
}

// ---------------------------------------------------------------------------
// XCD-chunked bijective block swizzle (m204).
// ---------------------------------------------------------------------------
__device__ __forceinline__ int xcd_swizzle(int fid, int nwg) {
  const int q = nwg >> 3, r = nwg & 7, x = fid & 7, o = fid >> 3;
  return (x < r ? x*(q+1) : r*(q+1) + (x-r)*q) + o;
}

// ---------------------------------------------------------------------------
// RING GEMM, INT8 (r8-proven ring ported to i8): 3-buffer, depth-2 prefetch,
// counted vmcnt, ONE barrier/K-step. K-step 64, mfma_i32_16x16x64_i8.
// out[M,N] = epi( sx[row] * scl[col] * (A8[M,K] @ W8[N,K]^T) ), f32 out.
// BN=128. EPI: 0 none, 2 +resid, 3 sigmoid iff col<D.
// SPLITK: gridDim.z pieces write outp + z*M*N.
// ---------------------------------------------------------------------------
template<int BM, int NW, int EPI, bool SPLITK = false>
__global__ __launch_bounds__(NW*64) void gemm_i8_kernel(
    const char* __restrict__ A, const char* __restrict__ Bq,
    const float* __restrict__ sx, const float* __restrict__ scl,
    const float* __restrict__ resid, float* __restrict__ outp, int N, int K)
{
  constexpr int WN = 2;
  constexpr int WM = NW / WN;
  constexpr int MF = BM / (WM*16);
  constexpr int ACALLS = BM / (16*NW);
  constexpr int BCALLS = 128 / (16*NW);
  constexpr int VCNT = ACALLS + BCALLS;
  __shared__ __align__(16) char As[3][BM*64];
  __shared__ __align__(16) char Bs[3][128*64];

  const int tid = threadIdx.x;
  const int wave = tid >> 6, lane = tid & 63;
  const int gx = gridDim.x, nwg = gx * gridDim.y;
  const int wg = xcd_swizzle(blockIdx.x + blockIdx.y*gx, nwg);
  const int m0 = (wg % gx) * BM, n0 = (wg / gx) * 128;
  const int lr = lane & 15, kg = lane >> 4;
  const int wm0 = (wave / WN) * (MF*16), wn0 = (wave % WN) * 64;
  const int grow = lane >> 2;            // staging: lane -> row in 16-row chunk
  const int gcol = (lane & 3) * 16;      // staging: lane -> 16-i8 col block
  const char* Ab = A  + (size_t)(m0 + grow)*K + gcol;
  const char* Bb = Bq + (size_t)(n0 + grow)*K + gcol;

  int kbeg = 0, kend = K;
  size_t obase = 0;
  if (SPLITK) {
    const int kc = K / gridDim.z;
    kbeg = blockIdx.z * kc; kend = kbeg + kc;
    obase = (size_t)blockIdx.z * M * (size_t)N;
  }
  const int NKT = (kend - kbeg) / 64;

  auto stage = [&](int buf, int k0) {
    #pragma unroll
    for (int c = 0; c < ACALLS; ++c) {
      const int rb = (c*NW + wave) * 16;
      gload16b(Ab + (size_t)rb*K + k0, &As[buf][rb*64]);
    }
    #pragma unroll
    for (int c = 0; c < BCALLS; ++c) {
      const int rb = (c*NW + wave) * 16;
      gload16b(Bb + (size_t)rb*K + k0, &Bs[buf][rb*64]);
    }
  };

  i32x4 acc[MF][4] = {};
  stage(0, kbeg);
  stage(1, kbeg + 64);

  int cur = 0;
  for (int t = 0; t < NKT; ++t) {
    vm_wait<VCNT>();
    ring_barrier();
    if (t + 2 < NKT) {
      int nb = cur + 2; if (nb >= 3) nb -= 3;
      stage(nb, kbeg + (t + 2) * 64);
    }
    i32x4 af[MF], bf[4];
    #pragma unroll
    for (int i = 0; i < MF; ++i)
      af[i] = *reinterpret_cast<const i32x4*>(&As[cur][(wm0 + i*16 + lr)*64 + kg*16]);
    #pragma unroll
    for (int j = 0; j < 4; ++j)
      bf[j] = *reinterpret_cast<const i32x4*>(&Bs[cur][(wn0 + j*16 + lr)*64 + kg*16]);
    #pragma unroll
    for (int i = 0; i < MF; ++i)
      #pragma unroll
      for (int j = 0; j < 4; ++j)
        acc[i][j] = __builtin_amdgcn_mfma_i32_16x16x64_i8(af[i], bf[j], acc[i][j], 0, 0, 0);
    ++cur; if (cur == 3) cur = 0;
  }

  // C/D frag layout: col=lane&15, row=(lane>>4)*4+e (dtype-independent)
  #pragma unroll
  for (int j = 0; j < 4; ++j) {
    const int col = n0 + wn0 + j*16 + lr;
    const float sv = scl[col];
    #pragma unroll
    for (int i = 0; i < MF; ++i) {
      #pragma unroll
      for (int e = 0; e < 4; ++e) {
        const int row = m0 + wm0 + i*16 + kg*4 + e;
        float y = (float)acc[i][j][e] * sx[row] * sv;
        if (EPI == 3 && col < D) y = 1.f / (1.f + expf(-y));
        if (EPI == 2) y += resid[(size_t)row*N + col];
        outp[obase + (size_t)row*N + col] = y;
      }
    }
  }
}

// ---------------------------------------------------------------------------
// RING HEAD GEMM, INT8 (r10-proven): 128x256 tile, 8 waves, K-step 64.
// ---------------------------------------------------------------------------
__global__ __launch_bounds__(512) void gemm_head_i8_kernel(
    const char* __restrict__ A, const char* __restrict__ Bq,
    const float* __restrict__ sx, const float* __restrict__ sw,
    float* __restrict__ out, int N, int K)
{
  constexpr int BM = 128, BN = 256;
  __shared__ __align__(16) char As[3][BM*64];
  __shared__ __align__(16) char Bs[3][BN*64];
  const int tid = threadIdx.x;
  const int wave = tid >> 6, lane = tid & 63;
  const int gx = gridDim.x, nwg = gx * gridDim.y;
  const int wg = xcd_swizzle(blockIdx.x + blockIdx.y*gx, nwg);
  const int m0 = (wg % gx) * BM, n0 = (wg / gx) * BN;
  const int lr = lane & 15, kg = lane >> 4;
  const int wm0 = (wave >> 2) * 64, wn0 = (wave & 3) * 64;
  const int grow = lane >> 2;
  const int gcol = (lane & 3) * 16;
  const char* Ab = A  + (size_t)(m0 + grow)*K + gcol;
  const char* Bb = Bq + (size_t)(n0 + grow)*K + gcol;

  auto stage = [&](int buf, int k0) {
    gload16b(Ab + (size_t)(wave*16)*K + k0, &As[buf][(wave*16)*64]);
    gload16b(Bb + (size_t)(wave*16)*K + k0, &Bs[buf][(wave*16)*64]);
    gload16b(Bb + (size_t)((wave+8)*16)*K + k0, &Bs[buf][((wave+8)*16)*64]);
  };

  i32x4 acc[4][4] = {};
  stage(0, 0);
  stage(1, 64);

  const int NKT = K / 64;
  int cur = 0;
  for (int t = 0; t < NKT; ++t) {
    vm_wait<3>();
    ring_barrier();
    if (t + 2 < NKT) {
      int nb = cur + 2; if (nb >= 3) nb -= 3;
      stage(nb, (t + 2) * 64);
    }
    i32x4 af[4], bf[4];
    #pragma unroll
    for (int i = 0; i < 4; ++i)
      af[i] = *reinterpret_cast<const i32x4*>(&As[cur][(wm0 + i*16 + lr)*64 + kg*16]);
    #pragma unroll
    for (int j = 0; j < 4; ++j)
      bf[j] = *reinterpret_cast<const i32x4*>(&Bs[cur][(wn0 + j*16 + lr)*64 + kg*16]);
    #pragma unroll
    for (int i = 0; i < 4; ++i)
      #pragma unroll
      for (int j = 0; j < 4; ++j)
        acc[i][j] = __builtin_amdgcn_mfma_i32_16x16x64_i8(af[i], bf[j], acc[i][j], 0, 0, 0);
    ++cur; if (cur == 3) cur = 0;
  }
  #pragma unroll
  for (int j = 0; j < 4; ++j) {
    const int col = n0 + wn0 + j*16 + lr;
    const float scw = sw[col];
    #pragma unroll
    for (int i = 0; i < 4; ++i) {
      #pragma unroll
      for (int e = 0; e < 4; ++e) {
        const int row = m0 + wm0 + i*16 + kg*4 + e;
        out[(size_t)row*N + col] = (float)acc[i][j][e] * sx[row] * scw;
      }
    }
  }
}

// ---------------------------------------------------------------------------
// RING FUSED FFN GEMM, INT8: g16 = (f16)( silu(sx s1 accA) * (sx s2 accB) ).
// 128x128 tile, 8 waves, ring-3, K-step 64.
// ---------------------------------------------------------------------------
__global__ __launch_bounds__(512) void gemm_ffn_i8_kernel(
    const char* __restrict__ A, const char* __restrict__ B1, const char* __restrict__ B2,
    const float* __restrict__ sx, const float* __restrict__ s1, const float* __restrict__ s2,
    f16* __restrict__ outg, int N, int K)
{
  constexpr int BM = 128, BN = 128;
  __shared__ __align__(16) char As [3][BM*64];
  __shared__ __align__(16) char B1s[3][BN*64];
  __shared__ __align__(16) char B2s[3][BN*64];
  const int tid = threadIdx.x;
  const int wave = tid >> 6, lane = tid & 63;
  const int gx = gridDim.x, nwg = gx * gridDim.y;
  const int wg = xcd_swizzle(blockIdx.x + blockIdx.y*gx, nwg);
  const int m0 = (wg % gx) * BM, n0 = (wg / gx) * BN;
  const int lr = lane & 15, kg = lane >> 4;
  const int wm0 = (wave >> 1) * 32, wn0 = (wave & 1) * 64;  // 8 waves: 4M x 2N
  const int grow = lane >> 2;
  const int gcol = (lane & 3) * 16;
  const char* Ab  = A  + (size_t)(m0 + grow)*K + gcol;
  const char* B1b = B1 + (size_t)(n0 + grow)*K + gcol;
  const char* B2b = B2 + (size_t)(n0 + grow)*K + gcol;

  auto stage = [&](int buf, int k0) {
    const int rb = wave * 16;
    gload16b(Ab  + (size_t)rb*K + k0, &As [buf][rb*64]);
    gload16b(B1b + (size_t)rb*K + k0, &B1s[buf][rb*64]);
    gload16b(B2b + (size_t)rb*K + k0, &B2s[buf][rb*64]);
  };

  i32x4 aca[2][4] = {};
  i32x4 acb[2][4] = {};
  stage(0, 0);
  stage(1, 64);

  const int NKT = K / 64;
  int cur = 0;
  for (int t = 0; t < NKT; ++t) {
    vm_wait<3>();
    ring_barrier();
    if (t + 2 < NKT) {
      int nb = cur + 2; if (nb >= 3) nb -= 3;
      stage(nb, (t + 2) * 64);
    }
    i32x4 af[2], b1f[4], b2f[4];
    #pragma unroll
    for (int i = 0; i < 2; ++i)
      af[i] = *reinterpret_cast<const i32x4*>(&As[cur][(wm0 + i*16 + lr)*64 + kg*16]);
    #pragma unroll
    for (int j = 0; j < 4; ++j) {
      b1f[j] = *reinterpret_cast<const i32x4*>(&B1s[cur][(wn0 + j*16 + lr)*64 + kg*16]);
      b2f[j] = *reinterpret_cast<const i32x4*>(&B2s[cur][(wn0 + j*16 + lr)*64 + kg*16]);
    }
    #pragma unroll
    for (int i = 0; i < 2; ++i)
      #pragma unroll
      for (int j = 0; j < 4; ++j) {
        aca[i][j] = __builtin_amdgcn_mfma_i32_16x16x64_i8(af[i], b1f[j], aca[i][j], 0, 0, 0);
        acb[i][j] = __builtin_amdgcn_mfma_i32_16x16x64_i8(af[i], b2f[j], acb[i][j], 0, 0, 0);
      }
    ++cur; if (cur == 3) cur = 0;
  }
  #pragma unroll
  for (int j = 0; j < 4; ++j) {
    const int col = n0 + wn0 + j*16 + lr;
    const float sa = s1[col], sb = s2[col];
    #pragma unroll
    for (int i = 0; i < 2; ++i) {
      #pragma unroll
      for (int e = 0; e < 4; ++e) {
        const int row = m0 + wm0 + i*16 + kg*4 + e;
        const float srow = sx[row];
        const float a = (float)aca[i][j][e] * srow * sa;
        const float b = (float)acb[i][j][e] * srow * sb;
        outg[(size_t)row*N + col] = (f16)((a / (1.f + expf(-a))) * b);
      }
    }
  }
}

// ---------------------------------------------------------------------------
// FALLBACK GEMM: inline quantize from f32 weights (used if ws too small).
// ---------------------------------------------------------------------------
__global__ __launch_bounds__(64) void scales_kernel(
    const float* __restrict__ Wr, const float* __restrict__ Wk,
    const float* __restrict__ Wv, const float* __restrict__ Wo,
    const float* __restrict__ W1, const float* __restrict__ W2,
    const float* __restrict__ Woc, float* __restrict__ s)
{
  const int r = blockIdx.x, l = blockIdx.y;
  const float* base; int len;
  if (r < 4*D) {
    const int m = r >> 10, row = r & (D-1);
    const float* Wm = (m==0) ? Wr : (m==1) ? Wk : (m==2) ? Wv : Wo;
    base = Wm + (size_t)l*D*D + (size_t)row*D; len = D;
  } else if (r < 4*D + 2*FFD) {
    int row = r - 4*D;
    const float* Wm = (row < FFD) ? W1 : W2;
    if (row >= FFD) row -= FFD;
    base = Wm + (size_t)l*FFD*D + (size_t)row*D; len = D;
  } else {
    const int row = r - (4*D + 2*FFD);
    base = Woc + (size_t)l*D*FFD + (size_t)row*FFD; len = FFD;
  }
  float sum = 0.f;
  for (int i = threadIdx.x; i < len; i += 64) sum += fabsf(base[i]);
  #pragma unroll
  for (int off = 32; off > 0; off >>= 1) sum += __shfl_down(sum, off);
  if (threadIdx.x == 0)
    s[(size_t)l*ROWS_PER_LAYER + r] = fmaxf(sum / (float)len, 1e-5f);
}

template<int BM, int EPI, bool QUANT, bool OUTF16>
__global__ __launch_bounds__(256) void gemm_bt_kernel(
    const f16* __restrict__ A, const float* __restrict__ Bw,
    const float* __restrict__ scl, const float* __restrict__ resid,
    void* __restrict__ outp, int N, int K)
{
  constexpr int BN = 128, LDT = 40;
  constexpr int MF = (BM == 128) ? 4 : 2;
  __shared__ f16 As[BM*LDT];
  __shared__ f16 Bs[BN*LDT];
  const int tid = threadIdx.x;
  const int m0 = blockIdx.y * BM, n0 = blockIdx.x * BN;
  const int wave = tid >> 6, lane = tid & 63;
  const int lr = lane & 15, kg = lane >> 4;
  const int wm0 = (wave >> 1) * (MF*16), wn0 = (wave & 1) * 64;
  f32x4 acc[MF][4] = {};
  for (int k0 = 0; k0 < K; k0 += 32) {
    #pragma unroll
    for (int c = 0; c < (BM*4)/256; ++c) {
      const int chunk = tid + c*256;
      const int row = chunk >> 2, c8 = (chunk & 3) << 3;
      *reinterpret_cast<f16x8*>(&As[row*LDT + c8]) =
        *reinterpret_cast<const f16x8*>(A + (size_t)(m0+row)*K + k0 + c8);
    }
    #pragma unroll
    for (int c = 0; c < 2; ++c) {
      const int chunk = tid + c*256;
      const int row = chunk >> 2, c8 = (chunk & 3) << 3;
      const float* bp = Bw + (size_t)(n0+row)*K + k0 + c8;
      const float4 f0 = *reinterpret_cast<const float4*>(bp);
      const float4 f1 = *reinterpret_cast<const float4*>(bp + 4);
      const float wv[8] = {f0.x,f0.y,f0.z,f0.w,f1.x,f1.y,f1.z,f1.w};
      f16x8 qv;
      if (QUANT) {
        const float hs = 0.5f * scl[n0+row];
        #pragma unroll
        for (int j = 0; j < 8; ++j)
          qv[j] = wv[j] > hs ? (f16)1.f : (wv[j] < -hs ? (f16)(-1.f) : (f16)0.f);
      } else {
        #pragma unroll
        for (int j = 0; j < 8; ++j) qv[j] = (f16)wv[j];
      }
      *reinterpret_cast<f16x8*>(&Bs[row*LDT + c8]) = qv;
    }
    __syncthreads();
    f16x8 af[MF], bf[4];
    #pragma unroll
    for (int i = 0; i < MF; ++i)
      af[i] = *reinterpret_cast<const f16x8*>(&As[(wm0 + i*16 + lr)*LDT + kg*8]);
    #pragma unroll
    for (int j = 0; j < 4; ++j)
      bf[j] = *reinterpret_cast<const f16x8*>(&Bs[(wn0 + j*16 + lr)*LDT + kg*8]);
    #pragma unroll
    for (int i = 0; i < MF; ++i)
      #pragma unroll
      for (int j = 0; j < 4; ++j)
        acc[i][j] = __builtin_amdgcn_mfma_f32_16x16x32_f16(af[i], bf[j], acc[i][j], 0, 0, 0);
    __syncthreads();
  }
  #pragma unroll
  for (int j = 0; j < 4; ++j) {
    const int col = n0 + wn0 + j*16 + lr;
    const float sv = QUANT ? scl[col] : 1.f;
    #pragma unroll
    for (int i = 0; i < MF; ++i) {
      #pragma unroll
      for (int e = 0; e < 4; ++e) {
        const int row = m0 + wm0 + i*16 + kg*4 + e;
        float y = acc[i][j][e] * sv;
        if (EPI == 1) y = 1.f / (1.f + expf(-y));
        if (EPI == 2) y += resid[(size_t)row*N + col];
        if (OUTF16) reinterpret_cast<f16*>(outp)[(size_t)row*N + col] = (f16)y;
        else        reinterpret_cast<float*>(outp)[(size_t)row*N + col] = y;
      }
    }
  }
}

// ---------------------------------------------------------------------------
extern "C" void kernel_launch(void* const* d_in, const int* in_sizes, int n_in,
                              void* d_out, int out_size, void* d_ws, size_t ws_size,
                              hipStream_t stream)
{
  (void)in_sizes; (void)n_in; (void)out_size;
  const int*   idx      = (const int*)  d_in[0];
  const float* embed    = (const float*)d_in[1];
  const float* ln_in_w  = (const float*)d_in[2];
  const float* ln1_w    = (const float*)d_in[3];
  const float* Wr       = (const float*)d_in[4];
  const float* Wk       = (const float*)d_in[5];
  const float* Wv       = (const float*)d_in[6];
  const float* Wo_t     = (const float*)d_in[7];
  const float* decay    = (const float*)d_in[8];
  const float* lnx_w    = (const float*)d_in[9];
  const float* ln2_w    = (const float*)d_in[10];
  const float* W1       = (const float*)d_in[11];
  const float* W2       = (const float*)d_in[12];
  const float* Wo_c     = (const float*)d_in[13];
  const float* ln_out_w = (const float*)d_in[14];
  float* out = (float*)d_out;

  char* p = (char*)d_ws;
  auto alloc = [&](size_t bytes) { void* q = (void*)p; p += (bytes + 255) & ~(size_t)255; return q; };
  float* h      = (float*)alloc((size_t)M*D*sizeof(float));
  f16*   xn     = (f16*)  alloc((size_t)M*D*sizeof(f16));       // fallback only
  float* rkv    = (float*)alloc((size_t)M*RKV*sizeof(float));   // r|k|v; reused as split-K partials
  float* rsb    = (float*)alloc((size_t)M*D*sizeof(float));
  f16*   abf    = (f16*)  alloc((size_t)M*FFD*sizeof(f16));
  f16*   bbf    = (f16*)  alloc((size_t)M*FFD*sizeof(f16));     // fallback only
  float* scales = (float*)alloc((size_t)NL*ROWS_PER_LAYER*sizeof(float));
  float* part   = (float*)alloc((size_t)BB*NT*D*sizeof(float));
  const size_t base_need = (size_t)(p - (char*)d_ws);
  const size_t fast_need = base_need + (NL*QL + 256)
      + ((size_t)V*D + 256) + (V*sizeof(float) + 256)
      + ((size_t)M*D + 256) + (M*sizeof(float) + 256)
      + ((size_t)M*FFD + 256) + (M*sizeof(float) + 256);

  embed_rms_kernel<<<M, 256, 0, stream>>>(idx, embed, ln_in_w, h);

  const dim3 gS(D/256, NT, BB);   // scan1/scan23: 512 blocks
  const dim3 gS2(D/256, BB);      // scan2 (fallback): 8 blocks

  if (ws_size >= fast_need) {
    // ================= FAST PATH: i8 weights + i8 activations =================
    char*  qw8  = (char*) alloc(NL*QL);
    char*  emb8 = (char*) alloc((size_t)V*D);
    float* sw   = (float*)alloc((size_t)V*sizeof(float));
    char*  xn8  = (char*) alloc((size_t)M*D);
    float* sx   = (float*)alloc((size_t)M*sizeof(float));
    char*  abf8 = (char*) alloc((size_t)M*FFD);
    float* sax  = (float*)alloc((size_t)M*sizeof(float));
    quant_kernel<<<dim3(ROWS_PER_LAYER, NL), 256, 0, stream>>>(Wr, Wk, Wv, Wo_t, W1, W2, Wo_c, qw8, scales);
    quant_embed_kernel<<<V, 256, 0, stream>>>(embed, emb8, sw);

    const dim3 gRKV(M/128, RKV/128);     // 16 x 24 = 384 blocks, 8 waves
    const dim3 gO(M/64, D/128);          // 32 x 8  = 256 blocks, 4 waves
    const dim3 gOC(M/64, D/128, 2);      // 512 blocks (split-K x2)
    const dim3 gFFN(M/128, FFD/128);     // 16 x 32 = 512 blocks, 8 waves
    const dim3 gHEAD(M/128, V/256);      // 16 x 125 = 2000 blocks, 8 waves

    rms_i8_kernel<<<M, 256, 0, stream>>>(h, ln1_w, xn8, sx);   // first layer's ln1
    for (int l = 0; l < NL; ++l) {
      const float* sl = scales + (size_t)l*ROWS_PER_LAYER;
      const char* qb = qw8 + (size_t)l*QL;
      const char *qrkv = qb, *qo = qb + 3ull*D*D;
      const char *q1 = qb + 4ull*D*D, *q2 = qb + 4ull*D*D + (size_t)FFD*D;
      const char *qoc = qb + 4ull*D*D + 2ull*(size_t)FFD*D;
      const float* dcy = decay + (size_t)l*D;
      // ---- time mix ----
      gemm_i8_kernel<128,8,3><<<gRKV, 512, 0, stream>>>(xn8, qrkv, sx, sl, nullptr, rkv, RKV, D);
      scan1_kernel<<<gS, 256, 0, stream>>>(rkv + D, rkv + 2*D, RKV, dcy, part);
      scan23_kernel<<<gS, 256, 0, stream>>>(rkv, rkv + D, rkv + 2*D, RKV, dcy, part, rsb);
      rms_i8_kernel<<<M, 256, 0, stream>>>(rsb, lnx_w + (size_t)l*D, xn8, sx);
      gemm_i8_kernel<64,4,2><<<gO, 256, 0, stream>>>(xn8, qo, sx, sl + 3*D, h, h, D, D);
      // ---- channel mix ----
      rms_i8_kernel<<<M, 256, 0, stream>>>(h, ln2_w + (size_t)l*D, xn8, sx);
      gemm_ffn_i8_kernel<<<gFFN, 512, 0, stream>>>(xn8, q1, q2, sx, sl + 4*D, sl + 4*D + FFD, abf, FFD, D);
      quant_ffn_kernel<<<M, 256, 0, stream>>>(abf, abf8, sax);
      gemm_i8_kernel<64,4,0,true><<<gOC, 256, 0, stream>>>(abf8, qoc, sax, sl + 4*D + 2*FFD, nullptr, rkv, D, FFD);
      const float* gnext = (l + 1 < NL) ? (ln1_w + (size_t)(l+1)*D) : ln_out_w;
      rms_radd_i8_kernel<<<M, 256, 0, stream>>>(h, rkv, rkv + (size_t)M*D, gnext, xn8, sx);
    }
    // ---- weight-tied head (A already i8 from last rms_radd) ----
    gemm_head_i8_kernel<<<gHEAD, 512, 0, stream>>>(xn8, emb8, sx, sw, out, V, D);
  } else {
    // ================= FALLBACK: inline-quant f16 path =================
    float* rbuf = rkv;
    float* kbuf = rkv + (size_t)M*D;
    float* vbuf = rkv + 2ull*M*D;
    scales_kernel<<<dim3(ROWS_PER_LAYER, NL), 64, 0, stream>>>(Wr, Wk, Wv, Wo_t, W1, W2, Wo_c, scales);
    const dim3 gD(D/128, M/64);
    const dim3 gF(FFD/128, M/128);
    for (int l = 0; l < NL; ++l) {
      const float* sl = scales + (size_t)l*ROWS_PER_LAYER;
      const float* dcy = decay + (size_t)l*D;
      rms_f16_kernel<<<M, 256, 0, stream>>>(h, ln1_w + (size_t)l*D, xn);
      gemm_bt_kernel<64,1,true,false><<<gD, 256, 0, stream>>>(xn, Wr + (size_t)l*D*D, sl,       nullptr, rbuf, D, D);
      gemm_bt_kernel<64,0,true,false><<<gD, 256, 0, stream>>>(xn, Wk + (size_t)l*D*D, sl + D,   nullptr, kbuf, D, D);
      gemm_bt_kernel<64,0,true,false><<<gD, 256, 0, stream>>>(xn, Wv + (size_t)l*D*D, sl + 2*D, nullptr, vbuf, D, D);
      scan1_kernel<<<gS, 256, 0, stream>>>(kbuf, vbuf, D, dcy, part);
      scan2_kernel<<<gS2, 256, 0, stream>>>(part);
      scan3_kernel<<<gS, 256, 0, stream>>>(rbuf, kbuf, vbuf, D, dcy, part, rsb);
      rms_f16_kernel<<<M, 256, 0, stream>>>(rsb, lnx_w + (size_t)l*D, xn);
      gemm_bt_kernel<64,2,true,false><<<gD, 256, 0, stream>>>(xn, Wo_t + (size_t)l*D*D, sl + 3*D, h, h, D, D);
      rms_f16_kernel<<<M, 256, 0, stream>>>(h, ln2_w + (size_t)l*D, xn);
      gemm_bt_kernel<128,0,true,true><<<gF, 256, 0, stream>>>(xn, W1 + (size_t)l*FFD*D, sl + 4*D,       nullptr, abf, FFD, D);
      gemm_bt_kernel<128,0,true,true><<<gF, 256, 0, stream>>>(xn, W2 + (size_t)l*FFD*D, sl + 4*D + FFD, nullptr, bbf, FFD, D);
      silumul_kernel<<<(M*FFD/4)/256, 256, 0, stream>>>(abf, bbf, abf, M*FFD/4);
      gemm_bt_kernel<64,2,true,false><<<gD, 256, 0, stream>>>(abf, Wo_c + (size_t)l*D*FFD, sl + 4*D + 2*FFD, h, h, D, FFD);
    }
    rms_f16_kernel<<<M, 256, 0, stream>>>(h, ln_out_w, xn);
    gemm_bt_kernel<128,0,false,false><<<dim3(V/128, M/128), 256, 0, stream>>>(xn, embed, nullptr, nullptr, out, V, D);
  }
}